// Round 16
// baseline (5314.085 us; speedup 1.0000x reference)
//
#include <hip/hip_runtime.h>
#include <hip/hip_bf16.h>
#include <hip/hip_fp16.h>

#define B_ 16
#define N_ 512
#define E_ 256
#define H_ 8
#define DH_ 32
#define L_ 6
#define DFF_ 1024
#define LSN 528

typedef unsigned short ushort_t;
typedef __attribute__((ext_vector_type(8))) short short8v;
typedef __attribute__((ext_vector_type(4))) float f32x4;
typedef __attribute__((ext_vector_type(2))) _Float16 half2v;
typedef __attribute__((ext_vector_type(8))) _Float16 half8v;

__device__ __forceinline__ float bf2f_raw(unsigned short u){
    unsigned int x = ((unsigned int)u) << 16; float f;
    __builtin_memcpy(&f, &x, 4); return f;
}
__device__ __forceinline__ unsigned short f2bf_rne(float f){
    unsigned int u; __builtin_memcpy(&u, &f, 4);
    u += 0x7fffu + ((u >> 16) & 1u);
    return (unsigned short)(u >> 16);
}
__device__ __forceinline__ unsigned int packbf2(float a, float b){
    return (unsigned int)f2bf_rne(a) | ((unsigned int)f2bf_rne(b) << 16);
}
__device__ __forceinline__ half2v u2hv(unsigned int u){ half2v h; __builtin_memcpy(&h, &u, 4); return h; }
__device__ __forceinline__ unsigned int hv2u(half2v h){ unsigned int u; __builtin_memcpy(&u, &h, 4); return u; }
__device__ __forceinline__ unsigned int pack2h(float a, float b){
    half2v h; h.x = (_Float16)a; h.y = (_Float16)b; return hv2u(h);
}
__device__ __forceinline__ ushort_t f2h_u(float f){
    _Float16 h = (_Float16)f; ushort_t u; __builtin_memcpy(&u, &h, 2); return u;
}
__device__ __forceinline__ float h2f_u(ushort_t u){
    _Float16 h; __builtin_memcpy(&h, &u, 2); return (float)h;
}
__device__ __forceinline__ float dot2h(unsigned int p, unsigned int v, float c){
#if __has_builtin(__builtin_amdgcn_fdot2)
    return __builtin_amdgcn_fdot2(u2hv(p), u2hv(v), c, false);
#else
    half2v a = u2hv(p), b = u2hv(v);
    return fmaf((float)a.y, (float)b.y, fmaf((float)a.x, (float)b.x, c));
#endif
}
__device__ __forceinline__ float gelu_f(float x){
    return 0.5f * x * (1.0f + erff(x * 0.7071067811865476f));
}

// ---------------- input normalization ----------------
__global__ void detect_and_mask(const unsigned int* __restrict__ lnS_raw,
                                const void* __restrict__ mask_raw,
                                int* __restrict__ flag, int* __restrict__ maskI){
    __shared__ int s_isbf, s_m32;
    if (threadIdx.x == 0){
        s_isbf = (lnS_raw[0] == 0x3F803F80u) ? 1 : 0;
        const unsigned int* mw = (const unsigned int*)mask_raw;
        int ok = 1;
        for (int k = 0; k < 64; k++){ if (mw[k] > 1u){ ok = 0; break; } }
        s_m32 = ok;
        *flag = s_isbf;
    }
    __syncthreads();
    if (s_m32){
        const int* mi = (const int*)mask_raw;
        for (int i = threadIdx.x; i < B_*N_; i += blockDim.x) maskI[i] = (mi[i] != 0);
    } else {
        const unsigned char* mb = (const unsigned char*)mask_raw;
        for (int i = threadIdx.x; i < B_*N_; i += blockDim.x) maskI[i] = (mb[i] != 0);
    }
}

struct CvtTable {
    const void* src[36];
    int off[37];
    int dstoff[36];
};

__global__ __launch_bounds__(256) void cvt_all(CvtTable t, float* __restrict__ base,
                                               const int* __restrict__ flag){
    int gi = blockIdx.x * 256 + threadIdx.x;
    if (gi >= t.off[36]) return;
    int seg = 0;
    for (int s = 1; s < 36; s++) if (gi >= t.off[s]) seg = s;
    int loc = gi - t.off[seg];
    float* dst = base + t.dstoff[seg] + loc;
    if (*flag) *dst = bf2f_raw(((const unsigned short*)t.src[seg])[loc]);
    else       *dst = ((const float*)t.src[seg])[loc];
}

// ---------------- weight transpose-pack: f32 [K][N] -> bf16 [N][K] ----------------
struct TPTable {
    const float* src[24];
    ushort_t* dst[24];
    int K[24], N[24];
    int tile0[25];
};

__global__ __launch_bounds__(256) void wpack(TPTable tp){
    int bid = blockIdx.x;
    int m = 0;
    while (m + 1 < 24 && bid >= tp.tile0[m+1]) m++;
    int t = bid - tp.tile0[m];
    int tiles_n = tp.N[m] >> 5;
    int tk = t / tiles_n, tn = t - tk*tiles_n;
    __shared__ float tile[32][33];
    int tx = threadIdx.x & 31, ty = threadIdx.x >> 5;
    const float* src = tp.src[m];
    int Nn = tp.N[m], Kk = tp.K[m];
    #pragma unroll
    for (int r = 0; r < 4; r++){
        int k = tk*32 + ty + r*8;
        tile[ty + r*8][tx] = src[(size_t)k*Nn + tn*32 + tx];
    }
    __syncthreads();
    ushort_t* dst = tp.dst[m];
    #pragma unroll
    for (int r = 0; r < 4; r++){
        int n = tn*32 + ty + r*8;
        dst[(size_t)n*Kk + tk*32 + tx] = f2bf_rne(tile[tx][ty + r*8]);
    }
}

// ---------------- V transpose to f16: VT[b][d][n] ----------------
__global__ __launch_bounds__(256) void vT_pack(const float* __restrict__ qkv,
                                               ushort_t* __restrict__ VTf){
    __shared__ float t[32][33];
    int b = blockIdx.z;
    int n0 = blockIdx.x * 32, d0 = blockIdx.y * 32;
    int tx = threadIdx.x & 31, ty = threadIdx.x >> 5;
    #pragma unroll
    for (int r = 0; r < 4; r++){
        int n = ty + r*8;
        t[n][tx] = qkv[(size_t)(b*N_ + n0 + n)*768 + 512 + d0 + tx];
    }
    __syncthreads();
    #pragma unroll
    for (int r = 0; r < 4; r++){
        int d = ty + r*8;
        VTf[(size_t)(b*E_ + d0 + d)*N_ + n0 + tx] = f2h_u(t[tx][d]);
    }
}

// ---------------- pair-feature normalization stats ----------------
__global__ __launch_bounds__(256) void pair_stats(const float* __restrict__ hits,
                                                  float* __restrict__ ppart){
    int blk = blockIdx.x;
    int b = blk >> 5, chunk = blk & 31;
    int tid = threadIdx.x;
    float acc[6] = {0,0,0,0,0,0};
    for (int ii = 0; ii < 16; ii++){
        int i = chunk*16 + ii;
        const float* hi = hits + (size_t)(b*N_ + i)*5;
        float h0=hi[0], h1=hi[1], h2=hi[2], h3=hi[3], h4=hi[4];
        for (int j = tid; j < N_; j += 256){
            const float* hj = hits + (size_t)(b*N_ + j)*5;
            float dx = h0 - hj[0], dy = h1 - hj[1];
            acc[0] += fabsf(dx);
            acc[1] += fabsf(dy);
            acc[2] += sqrtf(dx*dx + dy*dy + 1e-6f);
            acc[3] += fabsf(h2 - hj[2]);
            acc[4] += fabsf(h3 - hj[3]);
            acc[5] += fabsf(h4 - hj[4]);
        }
    }
    __shared__ float red[256];
    for (int c = 0; c < 6; c++){
        red[tid] = acc[c]; __syncthreads();
        for (int s = 128; s > 0; s >>= 1){ if (tid < s) red[tid] += red[tid+s]; __syncthreads(); }
        if (tid == 0) ppart[(size_t)(b*32 + chunk)*6 + c] = red[0];
        __syncthreads();
    }
}

__global__ void pair_fin(const float* __restrict__ ppart, float* __restrict__ pscale){
    int t = threadIdx.x;
    if (t >= B_*6) return;
    int b = t / 6, c = t % 6;
    float s = 0.f;
    for (int k = 0; k < 32; k++) s += ppart[(size_t)(b*32 + k)*6 + c];
    float mean = s * (1.0f / (float)(N_*N_));
    pscale[t] = 1.0f / (mean + 1e-6f);
}

// ---------------- embedding (dual f32+bf16 output) ----------------
__global__ __launch_bounds__(256) void embed_kernel(const float* __restrict__ hits,
        const float* __restrict__ ew, const float* __restrict__ eb,
        const float* __restrict__ lns, const float* __restrict__ lnb,
        const float* __restrict__ pw, const float* __restrict__ pb,
        float* __restrict__ feat, ushort_t* __restrict__ featb){
    int row = blockIdx.x; int e = threadIdx.x;
    const float* h = hits + (size_t)row*5;
    float h0=h[0], h1=h[1], h2=h[2], h3=h[3], h4=h[4];
    float t = eb[e] + h0*ew[e] + h1*ew[E_+e] + h2*ew[2*E_+e] + h3*ew[3*E_+e] + h4*ew[4*E_+e];
    __shared__ float red[256];
    red[e] = t; __syncthreads();
    for (int s = 128; s > 0; s >>= 1){ if (e < s) red[e] += red[e+s]; __syncthreads(); }
    float m = red[0] * (1.0f/E_); __syncthreads();
    float d = t - m;
    red[e] = d*d; __syncthreads();
    for (int s = 128; s > 0; s >>= 1){ if (e < s) red[e] += red[e+s]; __syncthreads(); }
    float v = red[0] * (1.0f/E_);
    float ln = d * rsqrtf(v + 1e-5f) * lns[e] + lnb[e];
    float g1 = gelu_f(ln);
    float p = pb[e] + h0*pw[e] + h1*pw[E_+e];
    float o = g1 + gelu_f(p);
    feat[(size_t)row*E_ + e] = o;
    featb[(size_t)row*E_ + e] = f2bf_rne(o);
}

// ---------------- bf16 MFMA GEMM ----------------
template<int ACT>
__global__ __launch_bounds__(256) void gemm_bf16(const ushort_t* __restrict__ A,
        const ushort_t* __restrict__ WT, const float* __restrict__ bias,
        float* __restrict__ C, ushort_t* __restrict__ Cbf, int M, int Ncols, int K){
    __shared__ __align__(16) ushort_t As[64][72];
    __shared__ __align__(16) ushort_t Bs[64][72];
    int tid = threadIdx.x;
    int mBase = blockIdx.y * 64, nBase = blockIdx.x * 64;
    int l = tid & 63, w = tid >> 6;
    int l15 = l & 15, lg = l >> 4;
    int wm = w >> 1, wn = w & 1;
    int srow = tid >> 2, skq = (tid & 3) * 16;
    f32x4 acc00 = {0.f,0.f,0.f,0.f}, acc01 = acc00, acc10 = acc00, acc11 = acc00;
    for (int kt = 0; kt < K; kt += 64){
        uint4 av0 = *(const uint4*)(A  + (size_t)(mBase+srow)*K + kt + skq);
        uint4 av1 = *(const uint4*)(A  + (size_t)(mBase+srow)*K + kt + skq + 8);
        uint4 bv0 = *(const uint4*)(WT + (size_t)(nBase+srow)*K + kt + skq);
        uint4 bv1 = *(const uint4*)(WT + (size_t)(nBase+srow)*K + kt + skq + 8);
        *(uint4*)&As[srow][skq]     = av0;
        *(uint4*)&As[srow][skq + 8] = av1;
        *(uint4*)&Bs[srow][skq]     = bv0;
        *(uint4*)&Bs[srow][skq + 8] = bv1;
        __syncthreads();
        #pragma unroll
        for (int ks = 0; ks < 2; ks++){
            short8v a0 = *(short8v*)&As[wm*32      + l15][ks*32 + lg*8];
            short8v a1 = *(short8v*)&As[wm*32 + 16 + l15][ks*32 + lg*8];
            short8v b0 = *(short8v*)&Bs[wn*32      + l15][ks*32 + lg*8];
            short8v b1 = *(short8v*)&Bs[wn*32 + 16 + l15][ks*32 + lg*8];
            acc00 = __builtin_amdgcn_mfma_f32_16x16x32_bf16(a0, b0, acc00, 0, 0, 0);
            acc01 = __builtin_amdgcn_mfma_f32_16x16x32_bf16(a0, b1, acc01, 0, 0, 0);
            acc10 = __builtin_amdgcn_mfma_f32_16x16x32_bf16(a1, b0, acc10, 0, 0, 0);
            acc11 = __builtin_amdgcn_mfma_f32_16x16x32_bf16(a1, b1, acc11, 0, 0, 0);
        }
        __syncthreads();
    }
    #pragma unroll
    for (int fm = 0; fm < 2; fm++){
        #pragma unroll
        for (int fn = 0; fn < 2; fn++){
            f32x4 a = (fm==0) ? ((fn==0)?acc00:acc01) : ((fn==0)?acc10:acc11);
            int col = nBase + wn*32 + fn*16 + l15;
            float bs = bias ? bias[col] : 0.f;
            #pragma unroll
            for (int r = 0; r < 4; r++){
                int row = mBase + wm*32 + fm*16 + lg*4 + r;
                float o = a[r] + bs;
                if (ACT == 1) o = gelu_f(o);
                if (C)   C[(size_t)row*Ncols + col] = o;
                if (Cbf) Cbf[(size_t)row*Ncols + col] = f2bf_rne(o);
            }
        }
    }
}

// ---------------- per-layer prepack into MFMA-direct tiles ----------------
__global__ __launch_bounds__(512) void pk_pack_tiled(const float* __restrict__ qkv,
        const float* __restrict__ hits, const float* __restrict__ pscale,
        const float* __restrict__ w1, uint4* __restrict__ PTt, uint4* __restrict__ Kt){
    int blk = blockIdx.x;               // b*32 + jblk16
    int b = blk >> 5;
    int jb16 = blk & 31;
    int tid = threadIdx.x;
    int ks = tid >> 6, l = tid & 63, l15 = l & 15, lg = l >> 4;
    int n = jb16*16 + l15;
    int row = b*N_ + n;
    const float* sc6 = pscale + b*6;
    const float* h = hits + (size_t)row*5;
    float a0 = h[0]*sc6[0], a1 = h[1]*sc6[1], a2 = h[2]*sc6[3], a3 = h[3]*sc6[4], a4 = h[4]*sc6[5];
    int c0 = ks*32 + lg*8;
    float p[8];
    #pragma unroll
    for (int e = 0; e < 8; e++){
        int c = c0 + e;
        p[e] = a0*w1[c] + a1*w1[E_+c] + a2*w1[3*E_+c] + a3*w1[4*E_+c] + a4*w1[5*E_+c];
    }
    uint4 up;
    up.x = pack2h(p[0], p[1]); up.y = pack2h(p[2], p[3]);
    up.z = pack2h(p[4], p[5]); up.w = pack2h(p[6], p[7]);
    const float* kr = qkv + (size_t)row*768 + 256 + c0;
    uint4 uk;
    uk.x = packbf2(kr[0], kr[1]); uk.y = packbf2(kr[2], kr[3]);
    uk.z = packbf2(kr[4], kr[5]); uk.w = packbf2(kr[6], kr[7]);
    size_t idx = ((size_t)blk*8 + ks)*64 + l;
    PTt[idx] = up;
    Kt[idx]  = uk;
}

// ---------------- A-fragment build (packed f16 native ops): max(bs - p + d*wd, 0) --------
__device__ __forceinline__ half8v build_afrag_h(uint4 pt, uint4 bs, uint4 wd, half2v d2){
    half2v z2 = (half2v)(_Float16)0;
    half2v r0 = d2 * u2hv(wd.x) + (u2hv(bs.x) - u2hv(pt.x));
    half2v r1 = d2 * u2hv(wd.y) + (u2hv(bs.y) - u2hv(pt.y));
    half2v r2 = d2 * u2hv(wd.z) + (u2hv(bs.z) - u2hv(pt.z));
    half2v r3 = d2 * u2hv(wd.w) + (u2hv(bs.w) - u2hv(pt.w));
    r0 = __builtin_elementwise_max(r0, z2);
    r1 = __builtin_elementwise_max(r1, z2);
    r2 = __builtin_elementwise_max(r2, z2);
    r3 = __builtin_elementwise_max(r3, z2);
    uint4 u;
    u.x = hv2u(r0); u.y = hv2u(r1); u.z = hv2u(r2); u.w = hv2u(r3);
    half8v r; __builtin_memcpy(&r, &u, 16); return r;
}

// ---------------- fused attention v12: same as v11 but 8 waves/SIMD target -----------------
// grid = B*(N/2) = 4096. x = bid&7 serves batches {2x, 2x+1} (L2-resident slabs per XCD).
__global__ __launch_bounds__(512, 8) void attn12_kernel(
        const float* __restrict__ qkv, const uint4* __restrict__ PTt,
        const uint4* __restrict__ Kt, const ushort_t* __restrict__ VTf,
        const float* __restrict__ hits,
        const int* __restrict__ maskI, const float* __restrict__ pscale,
        const float* __restrict__ b1, const float* __restrict__ w1,
        const float* __restrict__ w2, const float* __restrict__ b2,
        ushort_t* __restrict__ attnob){
    __shared__ __align__(16) ushort_t Ls[2][H_][LSN];
    __shared__ __align__(16) uint4 w2f[8][64];
    __shared__ __align__(16) unsigned int baseH[2][128];
    __shared__ __align__(16) unsigned int w1dH[128];
    __shared__ float distS[2][N_];
    __shared__ unsigned char mS[N_];
    __shared__ float b2S[8];
    __shared__ float inv_s[2][H_];

    int bid = blockIdx.x;
    int x = bid & 7, k = bid >> 3;          // k in [0,512)
    int b = 2*x + (k >> 8);
    int i0 = (k & 255) * 2;
    int tid = threadIdx.x;
    int l = tid & 63, w = tid >> 6;
    int l15 = l & 15, lg = l >> 4;
    const float scale = 0.17677669529663687f;

    // ---- staging ----
    if (tid < 256){
        int q = tid >> 7, cp = tid & 127;
        int c = cp*2;
        const float* sc6 = pscale + b*6;
        const float* hr = hits + (size_t)(b*N_ + i0 + q)*5;
        float pa = hr[0]*sc6[0]*w1[c] + hr[1]*sc6[1]*w1[E_+c] + hr[2]*sc6[3]*w1[3*E_+c]
                 + hr[3]*sc6[4]*w1[4*E_+c] + hr[4]*sc6[5]*w1[5*E_+c] + b1[c];
        float pb2 = hr[0]*sc6[0]*w1[c+1] + hr[1]*sc6[1]*w1[E_+c+1] + hr[2]*sc6[3]*w1[3*E_+c+1]
                  + hr[3]*sc6[4]*w1[4*E_+c+1] + hr[4]*sc6[5]*w1[5*E_+c+1] + b1[c+1];
        baseH[q][cp] = pack2h(pa, pb2);
        if (tid < 128){
            float wa = sc6[2]*w1[2*E_ + c], wb = sc6[2]*w1[2*E_ + c + 1];
            w1dH[cp] = pack2h(wa, wb);
        }
        if (tid < 8) b2S[tid] = b2[tid];
    }
    {
        int ks = tid >> 6, lv = tid & 63;
        int h = lv & 15, g = lv >> 4;
        uint4 u = {0u,0u,0u,0u};
        if (h < 8){
            int cb = ks*32 + g*8;
            const float* wp = w2 + (size_t)cb*H_ + h;
            u.x = pack2h(wp[0*H_], wp[1*H_]);
            u.y = pack2h(wp[2*H_], wp[3*H_]);
            u.z = pack2h(wp[4*H_], wp[5*H_]);
            u.w = pack2h(wp[6*H_], wp[7*H_]);
        }
        w2f[ks][lv] = u;
    }
    for (int idx = tid; idx < 1024; idx += 512){
        int q = idx >> 9, j = idx & 511;
        const float* hi = hits + (size_t)(b*N_ + i0 + q)*5;
        const float* hj = hits + (size_t)(b*N_ + j)*5;
        float dx = hi[0] - hj[0], dy = hi[1] - hj[1];
        distS[q][j] = sqrtf(dx*dx + dy*dy + 1e-6f);
        if (q == 0) mS[j] = (unsigned char)(maskI[b*N_ + j] != 0);
    }
    uint4 qz = {0u,0u,0u,0u};
    short8v zero8 = *(short8v*)&qz;
    short8v qreg0 = zero8, qreg1 = zero8;
    if (l15 < 8){
        const float* Q0 = qkv + (size_t)(b*N_ + i0    )*768 + l15*32 + lg*8;
        const float* Q1 = qkv + (size_t)(b*N_ + i0 + 1)*768 + l15*32 + lg*8;
        uint4 u0, u1;
        u0.x = packbf2(Q0[0]*scale, Q0[1]*scale); u0.y = packbf2(Q0[2]*scale, Q0[3]*scale);
        u0.z = packbf2(Q0[4]*scale, Q0[5]*scale); u0.w = packbf2(Q0[6]*scale, Q0[7]*scale);
        u1.x = packbf2(Q1[0]*scale, Q1[1]*scale); u1.y = packbf2(Q1[2]*scale, Q1[3]*scale);
        u1.z = packbf2(Q1[4]*scale, Q1[5]*scale); u1.w = packbf2(Q1[6]*scale, Q1[7]*scale);
        qreg0 = *(short8v*)&u0; qreg1 = *(short8v*)&u1;
    }
    __syncthreads();

    // ---- MFMA logits: merged ks loop (8 tile loads + 16 MFMAs per iter) ----
    int jb = w << 6;
    const uint4* PTb = PTt + (size_t)b*16384;
    const uint4* Kb  = Kt  + (size_t)b*16384;
    f32x4 a00 = {0.f,0.f,0.f,0.f}, a01 = a00, a02 = a00, a03 = a00;
    f32x4 a10 = a00, a11 = a00, a12 = a00, a13 = a00;
    int j0 = jb + l15;
    half2v e00 = (half2v)(_Float16)distS[0][j0];
    half2v e01 = (half2v)(_Float16)distS[0][j0+16];
    half2v e02 = (half2v)(_Float16)distS[0][j0+32];
    half2v e03 = (half2v)(_Float16)distS[0][j0+48];
    half2v e10 = (half2v)(_Float16)distS[1][j0];
    half2v e11 = (half2v)(_Float16)distS[1][j0+16];
    half2v e12 = (half2v)(_Float16)distS[1][j0+32];
    half2v e13 = (half2v)(_Float16)distS[1][j0+48];
    int tbase = (w*4)*8;

    #pragma unroll
    for (int ks = 0; ks < 8; ks++){
        int cbase = ks*32 + lg*8;
        uint4 pt0 = PTb[(size_t)(tbase      + ks)*64 + l];
        uint4 pt1 = PTb[(size_t)(tbase + 8  + ks)*64 + l];
        uint4 pt2 = PTb[(size_t)(tbase + 16 + ks)*64 + l];
        uint4 pt3 = PTb[(size_t)(tbase + 24 + ks)*64 + l];
        uint4 k0 = Kb[(size_t)(tbase      + ks)*64 + l];
        uint4 k1 = Kb[(size_t)(tbase + 8  + ks)*64 + l];
        uint4 k2 = Kb[(size_t)(tbase + 16 + ks)*64 + l];
        uint4 k3 = Kb[(size_t)(tbase + 24 + ks)*64 + l];
        uint4 wfrag4 = w2f[ks][l];
        half8v wfrag; __builtin_memcpy(&wfrag, &wfrag4, 16);
        uint4 wd = *(uint4*)&w1dH[cbase >> 1];
        {
            uint4 bs = *(uint4*)&baseH[0][cbase >> 1];
            half8v f0 = build_afrag_h(pt0, bs, wd, e00);
            half8v f1 = build_afrag_h(pt1, bs, wd, e01);
            half8v f2 = build_afrag_h(pt2, bs, wd, e02);
            half8v f3 = build_afrag_h(pt3, bs, wd, e03);
            a00 = __builtin_amdgcn_mfma_f32_16x16x32_f16(f0, wfrag, a00, 0, 0, 0);
            a01 = __builtin_amdgcn_mfma_f32_16x16x32_f16(f1, wfrag, a01, 0, 0, 0);
            a02 = __builtin_amdgcn_mfma_f32_16x16x32_f16(f2, wfrag, a02, 0, 0, 0);
            a03 = __builtin_amdgcn_mfma_f32_16x16x32_f16(f3, wfrag, a03, 0, 0, 0);
        }
        {
            uint4 bs = *(uint4*)&baseH[1][cbase >> 1];
            half8v f0 = build_afrag_h(pt0, bs, wd, e10);
            half8v f1 = build_afrag_h(pt1, bs, wd, e11);
            half8v f2 = build_afrag_h(pt2, bs, wd, e12);
            half8v f3 = build_afrag_h(pt3, bs, wd, e13);
            a10 = __builtin_amdgcn_mfma_f32_16x16x32_f16(f0, wfrag, a10, 0, 0, 0);
            a11 = __builtin_amdgcn_mfma_f32_16x16x32_f16(f1, wfrag, a11, 0, 0, 0);
            a12 = __builtin_amdgcn_mfma_f32_16x16x32_f16(f2, wfrag, a12, 0, 0, 0);
            a13 = __builtin_amdgcn_mfma_f32_16x16x32_f16(f3, wfrag, a13, 0, 0, 0);
        }
        {
            short8v q0f = (l15 == ks) ? qreg0 : zero8;
            short8v q1f = (l15 == ks) ? qreg1 : zero8;
            short8v kf0 = *(short8v*)&k0, kf1 = *(short8v*)&k1, kf2 = *(short8v*)&k2, kf3 = *(short8v*)&k3;
            a00 = __builtin_amdgcn_mfma_f32_16x16x32_bf16(kf0, q0f, a00, 0, 0, 0);
            a01 = __builtin_amdgcn_mfma_f32_16x16x32_bf16(kf1, q0f, a01, 0, 0, 0);
            a02 = __builtin_amdgcn_mfma_f32_16x16x32_bf16(kf2, q0f, a02, 0, 0, 0);
            a03 = __builtin_amdgcn_mfma_f32_16x16x32_bf16(kf3, q0f, a03, 0, 0, 0);
            a10 = __builtin_amdgcn_mfma_f32_16x16x32_bf16(kf0, q1f, a10, 0, 0, 0);
            a11 = __builtin_amdgcn_mfma_f32_16x16x32_bf16(kf1, q1f, a11, 0, 0, 0);
            a12 = __builtin_amdgcn_mfma_f32_16x16x32_bf16(kf2, q1f, a12, 0, 0, 0);
            a13 = __builtin_amdgcn_mfma_f32_16x16x32_bf16(kf3, q1f, a13, 0, 0, 0);
        }
    }

    // ---- write logits (f16): D layout col=lane&15 (=h), row=(lane>>4)*4+r ----
    if (l15 < 8){
        float b2h = b2S[l15];
        ushort_t neg = f2h_u(-1e9f);
        #pragma unroll
        for (int r = 0; r < 4; r++){
            int jr0 = jb +  0 + lg*4 + r;
            int jr1 = jb + 16 + lg*4 + r;
            int jr2 = jb + 32 + lg*4 + r;
            int jr3 = jb + 48 + lg*4 + r;
            Ls[0][l15][jr0] = mS[jr0] ? f2h_u(a00[r] + b2h) : neg;
            Ls[0][l15][jr1] = mS[jr1] ? f2h_u(a01[r] + b2h) : neg;
            Ls[0][l15][jr2] = mS[jr2] ? f2h_u(a02[r] + b2h) : neg;
            Ls[0][l15][jr3] = mS[jr3] ? f2h_u(a03[r] + b2h) : neg;
            Ls[1][l15][jr0] = mS[jr0] ? f2h_u(a10[r] + b2h) : neg;
            Ls[1][l15][jr1] = mS[jr1] ? f2h_u(a11[r] + b2h) : neg;
            Ls[1][l15][jr2] = mS[jr2] ? f2h_u(a12[r] + b2h) : neg;
            Ls[1][l15][jr3] = mS[jr3] ? f2h_u(a13[r] + b2h) : neg;
        }
    }
    __syncthreads();

    // ---- softmax: 16 groups (q,h) x 32 lanes, barrier-free shfl reductions ----
    {
        int g = tid >> 5, lane = tid & 31;
        int sq = g >> 3, shh = g & 7;
        ushort_t* Li = &Ls[sq][shh][0];
        float m = -3e38f;
        for (int jj = lane; jj < N_; jj += 32) m = fmaxf(m, h2f_u(Li[jj]));
        #pragma unroll
        for (int s = 16; s > 0; s >>= 1) m = fmaxf(m, __shfl_xor(m, s, 32));
        float ss = 0.f;
        for (int jj = lane; jj < N_; jj += 32){
            float e = __expf(h2f_u(Li[jj]) - m);
            ushort_t us = f2h_u(e);
            Li[jj] = us;
            ss += h2f_u(us);
        }
        #pragma unroll
        for (int s = 16; s > 0; s >>= 1) ss += __shfl_xor(ss, s, 32);
        if (lane == 0) inv_s[sq][shh] = 1.0f / ss;
    }
    __syncthreads();

    // ---- PV: f16 dot2 against V^T rows, 4-way ILP ----
    {
        int q = tid >> 8, d = tid & 255, hh = d >> 5;
        const unsigned int* vtrow = (const unsigned int*)(VTf + (size_t)(b*E_ + d)*N_);
        const uint4* vp = (const uint4*)vtrow;
        const uint4* Lp = (const uint4*)&Ls[q][hh][0];
        float o0 = 0.f, o1 = 0.f, o2 = 0.f, o3 = 0.f;
        #pragma unroll 2
        for (int t2 = 0; t2 < N_/8; t2 += 4){
            uint4 v0 = vp[t2], v1 = vp[t2+1], v2 = vp[t2+2], v3 = vp[t2+3];
            uint4 p0 = Lp[t2], p1 = Lp[t2+1], p2 = Lp[t2+2], p3 = Lp[t2+3];
            o0 = dot2h(p0.x, v0.x, o0); o0 = dot2h(p0.y, v0.y, o0);
            o0 = dot2h(p0.z, v0.z, o0); o0 = dot2h(p0.w, v0.w, o0);
            o1 = dot2h(p1.x, v1.x, o1); o1 = dot2h(p1.y, v1.y, o1);
            o1 = dot2h(p1.z, v1.z, o1); o1 = dot2h(p1.w, v1.w, o1);
            o2 = dot2h(p2.x, v2.x, o2); o2 = dot2h(p2.y, v2.y, o2);
            o2 = dot2h(p2.z, v2.z, o2); o2 = dot2h(p2.w, v2.w, o2);
            o3 = dot2h(p3.x, v3.x, o3); o3 = dot2h(p3.y, v3.y, o3);
            o3 = dot2h(p3.z, v3.z, o3); o3 = dot2h(p3.w, v3.w, o3);
        }
        float o = (o0 + o1) + (o2 + o3);
        attnob[(size_t)(b*N_ + i0 + q)*E_ + d] = f2bf_rne(o * inv_s[q][hh]);
    }
}

// ---------------- residual + LayerNorm (dual output) ----------------
__global__ __launch_bounds__(256) void ln_add_kernel(const float* __restrict__ a,
        const float* __restrict__ bsrc, const float* __restrict__ s,
        const float* __restrict__ bb, float* __restrict__ out,
        ushort_t* __restrict__ outb){
    int row = blockIdx.x, e = threadIdx.x;
    float v = a[(size_t)row*E_ + e] + bsrc[(size_t)row*E_ + e];
    __shared__ float red[256];
    red[e] = v; __syncthreads();
    for (int t = 128; t > 0; t >>= 1){ if (e < t) red[e] += red[e+t]; __syncthreads(); }
    float m = red[0] * (1.0f/E_); __syncthreads();
    float d = v - m;
    red[e] = d*d; __syncthreads();
    for (int t = 128; t > 0; t >>= 1){ if (e < t) red[e] += red[e+t]; __syncthreads(); }
    float var = red[0] * (1.0f/E_);
    float o = d * rsqrtf(var + 1e-5f) * s[e] + bb[e];
    out[(size_t)row*E_ + e] = o;
    outb[(size_t)row*E_ + e] = f2bf_rne(o);
}

// ---------------- masked pooling ----------------
__global__ __launch_bounds__(256) void pool_kernel(const float* __restrict__ feat,
        const int* __restrict__ maskI, float* __restrict__ pooled){
    int b = blockIdx.x, e = threadIdx.x;
    __shared__ int ml[N_];
    for (int n = e; n < N_; n += 256) ml[n] = maskI[b*N_ + n];
    __syncthreads();
    float s = 0.f, mx = -1e30f; int cnt = 0;
    for (int n = 0; n < N_; n++){
        if (ml[n]){
            float v = feat[(size_t)(b*N_ + n)*E_ + e];
            s += v; mx = fmaxf(mx, v); cnt++;
        }
    }
    float mean = s / ((float)cnt + 1e-6f);
    if (cnt == 0) mx = mean;
    pooled[b*768 + e]       = mx;
    pooled[b*768 + 256 + e] = mean;
}

// ---------------- params MLP ----------------
__global__ __launch_bounds__(256) void pf_kernel(const float* __restrict__ params,
        const float* __restrict__ w1, const float* __restrict__ b1,
        const float* __restrict__ lns, const float* __restrict__ lnb,
        const float* __restrict__ w2, const float* __restrict__ b2,
        float* __restrict__ pooled){
    int b = blockIdx.x, e = threadIdx.x;
    __shared__ float red[256];
    __shared__ float pfn[256];
    float p0 = params[b*5+0], p1 = params[b*5+1], p2 = params[b*5+2], p3 = params[b*5+3], p4 = params[b*5+4];
    float t = b1[e] + p0*w1[e] + p1*w1[E_+e] + p2*w1[2*E_+e] + p3*w1[3*E_+e] + p4*w1[4*E_+e];
    t = gelu_f(t);
    red[e] = t; __syncthreads();
    for (int s = 128; s > 0; s >>= 1){ if (e < s) red[e] += red[e+s]; __syncthreads(); }
    float m = red[0] * (1.0f/E_); __syncthreads();
    float d = t - m;
    red[e] = d*d; __syncthreads();
    for (int s = 128; s > 0; s >>= 1){ if (e < s) red[e] += red[e+s]; __syncthreads(); }
    float v = red[0] * (1.0f/E_);
    pfn[e] = d * rsqrtf(v + 1e-5f) * lns[e] + lnb[e];
    __syncthreads();
    float u = b2[e];
    for (int c = 0; c < E_; c++) u += pfn[c] * w2[c*E_ + e];
    pooled[b*768 + 512 + e] = gelu_f(u);
}

// ---------------- classifier head ----------------
__global__ __launch_bounds__(512) void cls_kernel(const float* __restrict__ pooled,
        const float* __restrict__ w1, const float* __restrict__ b1,
        const float* __restrict__ w2, const float* __restrict__ b2,
        const float* __restrict__ w3, const float* __restrict__ b3,
        float* __restrict__ out){
    int b = blockIdx.x, t = threadIdx.x;
    __shared__ float hb[768];
    __shared__ float h1[512];
    __shared__ float h2[256];
    for (int idx = t; idx < 768; idx += 512) hb[idx] = pooled[b*768 + idx];
    __syncthreads();
    float a = b1[t];
    for (int c = 0; c < 768; c++) a += hb[c] * w1[c*512 + t];
    h1[t] = gelu_f(a);
    __syncthreads();
    if (t < 256){
        float a2 = b2[t];
        for (int c = 0; c < 512; c++) a2 += h1[c] * w2[c*256 + t];
        h2[t] = gelu_f(a2);
    }
    __syncthreads();
    if (t < 2){
        float a3 = b3[t];
        for (int c = 0; c < 256; c++) a3 += h2[c] * w3[c*2 + t];
        out[b*2 + t] = a3;
    }
}

extern "C" void kernel_launch(void* const* d_in, const int* in_sizes, int n_in,
                              void* d_out, int out_size, void* d_ws, size_t ws_size,
                              hipStream_t stream){
    enum { I_HITS=0, I_MASK=1, I_PARAMS=2, I_EMBED_W=3, I_EMBED_B=4, I_ELN_S=5, I_ELN_B=6,
           I_POS_W=7, I_POS_B=8, I_QKV_W=9, I_OUT_W=10, I_OUT_B=11, I_PW1=12, I_PB1=13,
           I_PW2=14, I_PB2=15, I_FW1=16, I_FB1=17, I_FW2=18, I_FB2=19, I_N1S=20, I_N1B=21,
           I_N2S=22, I_N2B=23, I_PFW1=24, I_PFB1=25, I_PFLS=26, I_PFLB=27, I_PFW2=28, I_PFB2=29,
           I_CW1=30, I_CB1=31, I_CW2=32, I_CB2=33, I_CW3=34, I_CB3=35 };
    (void)n_in; (void)out_size; (void)ws_size;

    float* wsf = (float*)d_ws;
    int* maskI = (int*)d_ws;
    int* flag  = (int*)d_ws + 8192;
    size_t off = 8448;

    CvtTable tbl;
    float* cv[36];
    for (int idx = 0; idx < 36; idx++){
        if (idx == I_MASK){ cv[idx] = nullptr; tbl.src[idx] = d_in[idx]; tbl.dstoff[idx] = 0; continue; }
        cv[idx] = wsf + off;
        tbl.src[idx] = d_in[idx];
        tbl.dstoff[idx] = (int)off;
        off += (size_t)in_sizes[idx];
        off = (off + 3) & ~(size_t)3;
    }
    {
        int c2 = 0;
        for (int idx = 0; idx < 36; idx++){
            tbl.off[idx] = c2;
            if (idx != I_MASK) c2 += in_sizes[idx];
        }
        tbl.off[36] = c2;
    }

    float* feat  = wsf + off; off += (size_t)B_*N_*E_;
    float* qkv   = wsf + off; off += (size_t)B_*N_*3*E_;
    float* xbuf  = wsf + off; off += (size_t)B_*N_*E_;
    float* tmp   = wsf + off; off += (size_t)B_*N_*E_;
    float* ppart = wsf + off; off += (size_t)B_*32*6;
    float* pscale= wsf + off; off += (size_t)B_*6 + 2;
    float* pooled= wsf + off; off += (size_t)B_*768;
    ushort_t* featb  = (ushort_t*)(wsf + off); off += (size_t)B_*N_*E_/2;
    ushort_t* xbufb  = (ushort_t*)(wsf + off); off += (size_t)B_*N_*E_/2;
    ushort_t* attnob = (ushort_t*)(wsf + off); off += (size_t)B_*N_*E_/2;
    ushort_t* ffnhb  = (ushort_t*)(wsf + off); off += (size_t)B_*N_*DFF_/2;
    ushort_t* VTf    = (ushort_t*)(wsf + off); off += (size_t)B_*E_*N_/2;
    ushort_t* wtq = (ushort_t*)(wsf + off); off += (size_t)L_*768*E_/2;
    ushort_t* wto = (ushort_t*)(wsf + off); off += (size_t)L_*E_*E_/2;
    ushort_t* wt1 = (ushort_t*)(wsf + off); off += (size_t)L_*DFF_*E_/2;
    ushort_t* wt2 = (ushort_t*)(wsf + off); off += (size_t)L_*E_*DFF_/2;
    uint4* PTt = (uint4*)tmp;
    uint4* Kt  = PTt + (size_t)B_*16384;

    detect_and_mask<<<1, 256, 0, stream>>>((const unsigned int*)d_in[I_ELN_S], d_in[I_MASK], flag, maskI);
    {
        int total = tbl.off[36];
        cvt_all<<<(total + 255)/256, 256, 0, stream>>>(tbl, wsf, flag);
    }

    {
        TPTable tp;
        int t0 = 0;
        for (int l = 0; l < L_; l++){
            int m = l*4;
            tp.src[m+0] = cv[I_QKV_W] + (size_t)l*E_*3*E_; tp.dst[m+0] = wtq + (size_t)l*768*E_;
            tp.K[m+0] = E_;   tp.N[m+0] = 3*E_;
            tp.src[m+1] = cv[I_OUT_W] + (size_t)l*E_*E_;   tp.dst[m+1] = wto + (size_t)l*E_*E_;
            tp.K[m+1] = E_;   tp.N[m+1] = E_;
            tp.src[m+2] = cv[I_FW1] + (size_t)l*E_*DFF_;   tp.dst[m+2] = wt1 + (size_t)l*DFF_*E_;
            tp.K[m+2] = E_;   tp.N[m+2] = DFF_;
            tp.src[m+3] = cv[I_FW2] + (size_t)l*DFF_*E_;   tp.dst[m+3] = wt2 + (size_t)l*E_*DFF_;
            tp.K[m+3] = DFF_; tp.N[m+3] = E_;
        }
        for (int m = 0; m < 24; m++){
            tp.tile0[m] = t0;
            t0 += (tp.K[m] >> 5) * (tp.N[m] >> 5);
        }
        tp.tile0[24] = t0;
        wpack<<<t0, 256, 0, stream>>>(tp);
    }

    pair_stats<<<B_*32, 256, 0, stream>>>(cv[I_HITS], ppart);
    pair_fin<<<1, 128, 0, stream>>>(ppart, pscale);
    embed_kernel<<<B_*N_, 256, 0, stream>>>(cv[I_HITS], cv[I_EMBED_W], cv[I_EMBED_B],
                                            cv[I_ELN_S], cv[I_ELN_B], cv[I_POS_W], cv[I_POS_B],
                                            feat, featb);

    for (int l = 0; l < L_; l++){
        gemm_bf16<0><<<dim3(12,128), 256, 0, stream>>>(featb, wtq + (size_t)l*768*E_,
                                                       nullptr, qkv, nullptr, B_*N_, 3*E_, E_);
        pk_pack_tiled<<<B_*32, 512, 0, stream>>>(qkv, cv[I_HITS], pscale,
                                                 cv[I_PW1] + (size_t)l*6*E_, PTt, Kt);
        vT_pack<<<dim3(16,8,16), 256, 0, stream>>>(qkv, VTf);
        attn12_kernel<<<B_*(N_/2), 512, 0, stream>>>(qkv, PTt, Kt, VTf, cv[I_HITS], maskI, pscale,
                                               cv[I_PB1] + (size_t)l*6*E_ - (size_t)l*6*E_ + (size_t)l*E_,
                                               cv[I_PW1] + (size_t)l*6*E_,
                                               cv[I_PW2] + (size_t)l*E_*H_,
                                               cv[I_PB2] + (size_t)l*H_,
                                               attnob);
        gemm_bf16<0><<<dim3(4,128), 256, 0, stream>>>(attnob, wto + (size_t)l*E_*E_,
                                                      cv[I_OUT_B] + (size_t)l*E_, tmp, nullptr,
                                                      B_*N_, E_, E_);
        ln_add_kernel<<<B_*N_, 256, 0, stream>>>(feat, tmp, cv[I_N1S] + (size_t)l*E_,
                                                 cv[I_N1B] + (size_t)l*E_, xbuf, xbufb);
        gemm_bf16<1><<<dim3(16,128), 256, 0, stream>>>(xbufb, wt1 + (size_t)l*DFF_*E_,
                                                       cv[I_FB1] + (size_t)l*DFF_, nullptr, ffnhb,
                                                       B_*N_, DFF_, E_);
        gemm_bf16<0><<<dim3(4,128), 256, 0, stream>>>(ffnhb, wt2 + (size_t)l*E_*DFF_,
                                                      cv[I_FB2] + (size_t)l*E_, tmp, nullptr,
                                                      B_*N_, E_, DFF_);
        ln_add_kernel<<<B_*N_, 256, 0, stream>>>(xbuf, tmp, cv[I_N2S] + (size_t)l*E_,
                                                 cv[I_N2B] + (size_t)l*E_, feat, featb);
    }

    pool_kernel<<<B_, 256, 0, stream>>>(feat, maskI, pooled);
    pf_kernel<<<B_, 256, 0, stream>>>(cv[I_PARAMS], cv[I_PFW1], cv[I_PFB1],
                                      cv[I_PFLS], cv[I_PFLB], cv[I_PFW2], cv[I_PFB2], pooled);
    cls_kernel<<<B_, 512, 0, stream>>>(pooled, cv[I_CW1], cv[I_CB1], cv[I_CW2], cv[I_CB2],
                                       cv[I_CW3], cv[I_CB3], (float*)d_out);
}

// Round 17
// 2885.388 us; speedup vs baseline: 1.8417x; 1.8417x over previous
//
#include <hip/hip_runtime.h>
#include <hip/hip_bf16.h>
#include <hip/hip_fp16.h>

#define B_ 16
#define N_ 512
#define E_ 256
#define H_ 8
#define DH_ 32
#define L_ 6
#define DFF_ 1024
#define LSN 528

typedef unsigned short ushort_t;
typedef __attribute__((ext_vector_type(8))) short short8v;
typedef __attribute__((ext_vector_type(4))) float f32x4;
typedef __attribute__((ext_vector_type(2))) _Float16 half2v;
typedef __attribute__((ext_vector_type(8))) _Float16 half8v;

__device__ __forceinline__ float bf2f_raw(unsigned short u){
    unsigned int x = ((unsigned int)u) << 16; float f;
    __builtin_memcpy(&f, &x, 4); return f;
}
__device__ __forceinline__ unsigned short f2bf_rne(float f){
    unsigned int u; __builtin_memcpy(&u, &f, 4);
    u += 0x7fffu + ((u >> 16) & 1u);
    return (unsigned short)(u >> 16);
}
__device__ __forceinline__ unsigned int packbf2(float a, float b){
    return (unsigned int)f2bf_rne(a) | ((unsigned int)f2bf_rne(b) << 16);
}
__device__ __forceinline__ half2v u2hv(unsigned int u){ half2v h; __builtin_memcpy(&h, &u, 4); return h; }
__device__ __forceinline__ unsigned int hv2u(half2v h){ unsigned int u; __builtin_memcpy(&u, &h, 4); return u; }
__device__ __forceinline__ unsigned int pack2h(float a, float b){
    half2v h; h.x = (_Float16)a; h.y = (_Float16)b; return hv2u(h);
}
__device__ __forceinline__ ushort_t f2h_u(float f){
    _Float16 h = (_Float16)f; ushort_t u; __builtin_memcpy(&u, &h, 2); return u;
}
__device__ __forceinline__ float h2f_u(ushort_t u){
    _Float16 h; __builtin_memcpy(&h, &u, 2); return (float)h;
}
__device__ __forceinline__ float dot2h(unsigned int p, unsigned int v, float c){
#if __has_builtin(__builtin_amdgcn_fdot2)
    return __builtin_amdgcn_fdot2(u2hv(p), u2hv(v), c, false);
#else
    half2v a = u2hv(p), b = u2hv(v);
    return fmaf((float)a.y, (float)b.y, fmaf((float)a.x, (float)b.x, c));
#endif
}
__device__ __forceinline__ float gelu_f(float x){
    return 0.5f * x * (1.0f + erff(x * 0.7071067811865476f));
}

// ---------------- input normalization ----------------
__global__ void detect_and_mask(const unsigned int* __restrict__ lnS_raw,
                                const void* __restrict__ mask_raw,
                                int* __restrict__ flag, int* __restrict__ maskI){
    __shared__ int s_isbf, s_m32;
    if (threadIdx.x == 0){
        s_isbf = (lnS_raw[0] == 0x3F803F80u) ? 1 : 0;
        const unsigned int* mw = (const unsigned int*)mask_raw;
        int ok = 1;
        for (int k = 0; k < 64; k++){ if (mw[k] > 1u){ ok = 0; break; } }
        s_m32 = ok;
        *flag = s_isbf;
    }
    __syncthreads();
    if (s_m32){
        const int* mi = (const int*)mask_raw;
        for (int i = threadIdx.x; i < B_*N_; i += blockDim.x) maskI[i] = (mi[i] != 0);
    } else {
        const unsigned char* mb = (const unsigned char*)mask_raw;
        for (int i = threadIdx.x; i < B_*N_; i += blockDim.x) maskI[i] = (mb[i] != 0);
    }
}

struct CvtTable {
    const void* src[36];
    int off[37];
    int dstoff[36];
};

__global__ __launch_bounds__(256) void cvt_all(CvtTable t, float* __restrict__ base,
                                               const int* __restrict__ flag){
    int gi = blockIdx.x * 256 + threadIdx.x;
    if (gi >= t.off[36]) return;
    int seg = 0;
    for (int s = 1; s < 36; s++) if (gi >= t.off[s]) seg = s;
    int loc = gi - t.off[seg];
    float* dst = base + t.dstoff[seg] + loc;
    if (*flag) *dst = bf2f_raw(((const unsigned short*)t.src[seg])[loc]);
    else       *dst = ((const float*)t.src[seg])[loc];
}

// ---------------- weight transpose-pack: f32 [K][N] -> bf16 [N][K] ----------------
struct TPTable {
    const float* src[24];
    ushort_t* dst[24];
    int K[24], N[24];
    int tile0[25];
};

__global__ __launch_bounds__(256) void wpack(TPTable tp){
    int bid = blockIdx.x;
    int m = 0;
    while (m + 1 < 24 && bid >= tp.tile0[m+1]) m++;
    int t = bid - tp.tile0[m];
    int tiles_n = tp.N[m] >> 5;
    int tk = t / tiles_n, tn = t - tk*tiles_n;
    __shared__ float tile[32][33];
    int tx = threadIdx.x & 31, ty = threadIdx.x >> 5;
    const float* src = tp.src[m];
    int Nn = tp.N[m], Kk = tp.K[m];
    #pragma unroll
    for (int r = 0; r < 4; r++){
        int k = tk*32 + ty + r*8;
        tile[ty + r*8][tx] = src[(size_t)k*Nn + tn*32 + tx];
    }
    __syncthreads();
    ushort_t* dst = tp.dst[m];
    #pragma unroll
    for (int r = 0; r < 4; r++){
        int n = tn*32 + ty + r*8;
        dst[(size_t)n*Kk + tk*32 + tx] = f2bf_rne(tile[tx][ty + r*8]);
    }
}

// ---------------- V transpose to f16: VT[b][d][n] ----------------
__global__ __launch_bounds__(256) void vT_pack(const float* __restrict__ qkv,
                                               ushort_t* __restrict__ VTf){
    __shared__ float t[32][33];
    int b = blockIdx.z;
    int n0 = blockIdx.x * 32, d0 = blockIdx.y * 32;
    int tx = threadIdx.x & 31, ty = threadIdx.x >> 5;
    #pragma unroll
    for (int r = 0; r < 4; r++){
        int n = ty + r*8;
        t[n][tx] = qkv[(size_t)(b*N_ + n0 + n)*768 + 512 + d0 + tx];
    }
    __syncthreads();
    #pragma unroll
    for (int r = 0; r < 4; r++){
        int d = ty + r*8;
        VTf[(size_t)(b*E_ + d0 + d)*N_ + n0 + tx] = f2h_u(t[tx][d]);
    }
}

// ---------------- pair-feature normalization stats ----------------
__global__ __launch_bounds__(256) void pair_stats(const float* __restrict__ hits,
                                                  float* __restrict__ ppart){
    int blk = blockIdx.x;
    int b = blk >> 5, chunk = blk & 31;
    int tid = threadIdx.x;
    float acc[6] = {0,0,0,0,0,0};
    for (int ii = 0; ii < 16; ii++){
        int i = chunk*16 + ii;
        const float* hi = hits + (size_t)(b*N_ + i)*5;
        float h0=hi[0], h1=hi[1], h2=hi[2], h3=hi[3], h4=hi[4];
        for (int j = tid; j < N_; j += 256){
            const float* hj = hits + (size_t)(b*N_ + j)*5;
            float dx = h0 - hj[0], dy = h1 - hj[1];
            acc[0] += fabsf(dx);
            acc[1] += fabsf(dy);
            acc[2] += sqrtf(dx*dx + dy*dy + 1e-6f);
            acc[3] += fabsf(h2 - hj[2]);
            acc[4] += fabsf(h3 - hj[3]);
            acc[5] += fabsf(h4 - hj[4]);
        }
    }
    __shared__ float red[256];
    for (int c = 0; c < 6; c++){
        red[tid] = acc[c]; __syncthreads();
        for (int s = 128; s > 0; s >>= 1){ if (tid < s) red[tid] += red[tid+s]; __syncthreads(); }
        if (tid == 0) ppart[(size_t)(b*32 + chunk)*6 + c] = red[0];
        __syncthreads();
    }
}

__global__ void pair_fin(const float* __restrict__ ppart, float* __restrict__ pscale){
    int t = threadIdx.x;
    if (t >= B_*6) return;
    int b = t / 6, c = t % 6;
    float s = 0.f;
    for (int k = 0; k < 32; k++) s += ppart[(size_t)(b*32 + k)*6 + c];
    float mean = s * (1.0f / (float)(N_*N_));
    pscale[t] = 1.0f / (mean + 1e-6f);
}

// ---------------- embedding (dual f32+bf16 output) ----------------
__global__ __launch_bounds__(256) void embed_kernel(const float* __restrict__ hits,
        const float* __restrict__ ew, const float* __restrict__ eb,
        const float* __restrict__ lns, const float* __restrict__ lnb,
        const float* __restrict__ pw, const float* __restrict__ pb,
        float* __restrict__ feat, ushort_t* __restrict__ featb){
    int row = blockIdx.x; int e = threadIdx.x;
    const float* h = hits + (size_t)row*5;
    float h0=h[0], h1=h[1], h2=h[2], h3=h[3], h4=h[4];
    float t = eb[e] + h0*ew[e] + h1*ew[E_+e] + h2*ew[2*E_+e] + h3*ew[3*E_+e] + h4*ew[4*E_+e];
    __shared__ float red[256];
    red[e] = t; __syncthreads();
    for (int s = 128; s > 0; s >>= 1){ if (e < s) red[e] += red[e+s]; __syncthreads(); }
    float m = red[0] * (1.0f/E_); __syncthreads();
    float d = t - m;
    red[e] = d*d; __syncthreads();
    for (int s = 128; s > 0; s >>= 1){ if (e < s) red[e] += red[e+s]; __syncthreads(); }
    float v = red[0] * (1.0f/E_);
    float ln = d * rsqrtf(v + 1e-5f) * lns[e] + lnb[e];
    float g1 = gelu_f(ln);
    float p = pb[e] + h0*pw[e] + h1*pw[E_+e];
    float o = g1 + gelu_f(p);
    feat[(size_t)row*E_ + e] = o;
    featb[(size_t)row*E_ + e] = f2bf_rne(o);
}

// ---------------- bf16 MFMA GEMM ----------------
template<int ACT>
__global__ __launch_bounds__(256) void gemm_bf16(const ushort_t* __restrict__ A,
        const ushort_t* __restrict__ WT, const float* __restrict__ bias,
        float* __restrict__ C, ushort_t* __restrict__ Cbf, int M, int Ncols, int K){
    __shared__ __align__(16) ushort_t As[64][72];
    __shared__ __align__(16) ushort_t Bs[64][72];
    int tid = threadIdx.x;
    int mBase = blockIdx.y * 64, nBase = blockIdx.x * 64;
    int l = tid & 63, w = tid >> 6;
    int l15 = l & 15, lg = l >> 4;
    int wm = w >> 1, wn = w & 1;
    int srow = tid >> 2, skq = (tid & 3) * 16;
    f32x4 acc00 = {0.f,0.f,0.f,0.f}, acc01 = acc00, acc10 = acc00, acc11 = acc00;
    for (int kt = 0; kt < K; kt += 64){
        uint4 av0 = *(const uint4*)(A  + (size_t)(mBase+srow)*K + kt + skq);
        uint4 av1 = *(const uint4*)(A  + (size_t)(mBase+srow)*K + kt + skq + 8);
        uint4 bv0 = *(const uint4*)(WT + (size_t)(nBase+srow)*K + kt + skq);
        uint4 bv1 = *(const uint4*)(WT + (size_t)(nBase+srow)*K + kt + skq + 8);
        *(uint4*)&As[srow][skq]     = av0;
        *(uint4*)&As[srow][skq + 8] = av1;
        *(uint4*)&Bs[srow][skq]     = bv0;
        *(uint4*)&Bs[srow][skq + 8] = bv1;
        __syncthreads();
        #pragma unroll
        for (int ks = 0; ks < 2; ks++){
            short8v a0 = *(short8v*)&As[wm*32      + l15][ks*32 + lg*8];
            short8v a1 = *(short8v*)&As[wm*32 + 16 + l15][ks*32 + lg*8];
            short8v b0 = *(short8v*)&Bs[wn*32      + l15][ks*32 + lg*8];
            short8v b1 = *(short8v*)&Bs[wn*32 + 16 + l15][ks*32 + lg*8];
            acc00 = __builtin_amdgcn_mfma_f32_16x16x32_bf16(a0, b0, acc00, 0, 0, 0);
            acc01 = __builtin_amdgcn_mfma_f32_16x16x32_bf16(a0, b1, acc01, 0, 0, 0);
            acc10 = __builtin_amdgcn_mfma_f32_16x16x32_bf16(a1, b0, acc10, 0, 0, 0);
            acc11 = __builtin_amdgcn_mfma_f32_16x16x32_bf16(a1, b1, acc11, 0, 0, 0);
        }
        __syncthreads();
    }
    #pragma unroll
    for (int fm = 0; fm < 2; fm++){
        #pragma unroll
        for (int fn = 0; fn < 2; fn++){
            f32x4 a = (fm==0) ? ((fn==0)?acc00:acc01) : ((fn==0)?acc10:acc11);
            int col = nBase + wn*32 + fn*16 + l15;
            float bs = bias ? bias[col] : 0.f;
            #pragma unroll
            for (int r = 0; r < 4; r++){
                int row = mBase + wm*32 + fm*16 + lg*4 + r;
                float o = a[r] + bs;
                if (ACT == 1) o = gelu_f(o);
                if (C)   C[(size_t)row*Ncols + col] = o;
                if (Cbf) Cbf[(size_t)row*Ncols + col] = f2bf_rne(o);
            }
        }
    }
}

// ---------------- per-layer prepack into MFMA-direct tiles ----------------
__global__ __launch_bounds__(512) void pk_pack_tiled(const float* __restrict__ qkv,
        const float* __restrict__ hits, const float* __restrict__ pscale,
        const float* __restrict__ w1, uint4* __restrict__ PTt, uint4* __restrict__ Kt){
    int blk = blockIdx.x;               // b*32 + jblk16
    int b = blk >> 5;
    int jb16 = blk & 31;
    int tid = threadIdx.x;
    int ks = tid >> 6, l = tid & 63, l15 = l & 15, lg = l >> 4;
    int n = jb16*16 + l15;
    int row = b*N_ + n;
    const float* sc6 = pscale + b*6;
    const float* h = hits + (size_t)row*5;
    float a0 = h[0]*sc6[0], a1 = h[1]*sc6[1], a2 = h[2]*sc6[3], a3 = h[3]*sc6[4], a4 = h[4]*sc6[5];
    int c0 = ks*32 + lg*8;
    float p[8];
    #pragma unroll
    for (int e = 0; e < 8; e++){
        int c = c0 + e;
        p[e] = a0*w1[c] + a1*w1[E_+c] + a2*w1[3*E_+c] + a3*w1[4*E_+c] + a4*w1[5*E_+c];
    }
    uint4 up;
    up.x = pack2h(p[0], p[1]); up.y = pack2h(p[2], p[3]);
    up.z = pack2h(p[4], p[5]); up.w = pack2h(p[6], p[7]);
    const float* kr = qkv + (size_t)row*768 + 256 + c0;
    uint4 uk;
    uk.x = packbf2(kr[0], kr[1]); uk.y = packbf2(kr[2], kr[3]);
    uk.z = packbf2(kr[4], kr[5]); uk.w = packbf2(kr[6], kr[7]);
    size_t idx = ((size_t)blk*8 + ks)*64 + l;
    PTt[idx] = up;
    Kt[idx]  = uk;
}

// ---------------- A-fragment build (packed f16 native ops): max(bs - p + d*wd, 0) --------
__device__ __forceinline__ half8v build_afrag_h(uint4 pt, uint4 bs, uint4 wd, half2v d2){
    half2v z2 = (half2v)(_Float16)0;
    half2v r0 = d2 * u2hv(wd.x) + (u2hv(bs.x) - u2hv(pt.x));
    half2v r1 = d2 * u2hv(wd.y) + (u2hv(bs.y) - u2hv(pt.y));
    half2v r2 = d2 * u2hv(wd.z) + (u2hv(bs.z) - u2hv(pt.z));
    half2v r3 = d2 * u2hv(wd.w) + (u2hv(bs.w) - u2hv(pt.w));
    r0 = __builtin_elementwise_max(r0, z2);
    r1 = __builtin_elementwise_max(r1, z2);
    r2 = __builtin_elementwise_max(r2, z2);
    r3 = __builtin_elementwise_max(r3, z2);
    uint4 u;
    u.x = hv2u(r0); u.y = hv2u(r1); u.z = hv2u(r2); u.w = hv2u(r3);
    half8v r; __builtin_memcpy(&r, &u, 16); return r;
}

// ---------------- fused attention v11 (best known): merged ks-loop, shfl softmax, ILP PV ----
// grid = B*(N/2) = 4096. x = bid&7 serves batches {2x, 2x+1} (L2-resident slabs per XCD).
__global__ __launch_bounds__(512, 4) void attn11_kernel(
        const float* __restrict__ qkv, const uint4* __restrict__ PTt,
        const uint4* __restrict__ Kt, const ushort_t* __restrict__ VTf,
        const float* __restrict__ hits,
        const int* __restrict__ maskI, const float* __restrict__ pscale,
        const float* __restrict__ b1, const float* __restrict__ w1,
        const float* __restrict__ w2, const float* __restrict__ b2,
        ushort_t* __restrict__ attnob){
    __shared__ __align__(16) ushort_t Ls[2][H_][LSN];
    __shared__ __align__(16) uint4 w2f[8][64];
    __shared__ __align__(16) unsigned int baseH[2][128];
    __shared__ __align__(16) unsigned int w1dH[128];
    __shared__ float distS[2][N_];
    __shared__ unsigned char mS[N_];
    __shared__ float b2S[8];
    __shared__ float inv_s[2][H_];

    int bid = blockIdx.x;
    int x = bid & 7, k = bid >> 3;          // k in [0,512)
    int b = 2*x + (k >> 8);
    int i0 = (k & 255) * 2;
    int tid = threadIdx.x;
    int l = tid & 63, w = tid >> 6;
    int l15 = l & 15, lg = l >> 4;
    const float scale = 0.17677669529663687f;

    // ---- staging ----
    if (tid < 256){
        int q = tid >> 7, cp = tid & 127;
        int c = cp*2;
        const float* sc6 = pscale + b*6;
        const float* hr = hits + (size_t)(b*N_ + i0 + q)*5;
        float pa = hr[0]*sc6[0]*w1[c] + hr[1]*sc6[1]*w1[E_+c] + hr[2]*sc6[3]*w1[3*E_+c]
                 + hr[3]*sc6[4]*w1[4*E_+c] + hr[4]*sc6[5]*w1[5*E_+c] + b1[c];
        float pb2 = hr[0]*sc6[0]*w1[c+1] + hr[1]*sc6[1]*w1[E_+c+1] + hr[2]*sc6[3]*w1[3*E_+c+1]
                  + hr[3]*sc6[4]*w1[4*E_+c+1] + hr[4]*sc6[5]*w1[5*E_+c+1] + b1[c+1];
        baseH[q][cp] = pack2h(pa, pb2);
        if (tid < 128){
            float wa = sc6[2]*w1[2*E_ + c], wb = sc6[2]*w1[2*E_ + c + 1];
            w1dH[cp] = pack2h(wa, wb);
        }
        if (tid < 8) b2S[tid] = b2[tid];
    }
    {
        int ks = tid >> 6, lv = tid & 63;
        int h = lv & 15, g = lv >> 4;
        uint4 u = {0u,0u,0u,0u};
        if (h < 8){
            int cb = ks*32 + g*8;
            const float* wp = w2 + (size_t)cb*H_ + h;
            u.x = pack2h(wp[0*H_], wp[1*H_]);
            u.y = pack2h(wp[2*H_], wp[3*H_]);
            u.z = pack2h(wp[4*H_], wp[5*H_]);
            u.w = pack2h(wp[6*H_], wp[7*H_]);
        }
        w2f[ks][lv] = u;
    }
    for (int idx = tid; idx < 1024; idx += 512){
        int q = idx >> 9, j = idx & 511;
        const float* hi = hits + (size_t)(b*N_ + i0 + q)*5;
        const float* hj = hits + (size_t)(b*N_ + j)*5;
        float dx = hi[0] - hj[0], dy = hi[1] - hj[1];
        distS[q][j] = sqrtf(dx*dx + dy*dy + 1e-6f);
        if (q == 0) mS[j] = (unsigned char)(maskI[b*N_ + j] != 0);
    }
    uint4 qz = {0u,0u,0u,0u};
    short8v zero8 = *(short8v*)&qz;
    short8v qreg0 = zero8, qreg1 = zero8;
    if (l15 < 8){
        const float* Q0 = qkv + (size_t)(b*N_ + i0    )*768 + l15*32 + lg*8;
        const float* Q1 = qkv + (size_t)(b*N_ + i0 + 1)*768 + l15*32 + lg*8;
        uint4 u0, u1;
        u0.x = packbf2(Q0[0]*scale, Q0[1]*scale); u0.y = packbf2(Q0[2]*scale, Q0[3]*scale);
        u0.z = packbf2(Q0[4]*scale, Q0[5]*scale); u0.w = packbf2(Q0[6]*scale, Q0[7]*scale);
        u1.x = packbf2(Q1[0]*scale, Q1[1]*scale); u1.y = packbf2(Q1[2]*scale, Q1[3]*scale);
        u1.z = packbf2(Q1[4]*scale, Q1[5]*scale); u1.w = packbf2(Q1[6]*scale, Q1[7]*scale);
        qreg0 = *(short8v*)&u0; qreg1 = *(short8v*)&u1;
    }
    __syncthreads();

    // ---- MFMA logits: merged ks loop (8 tile loads + 16 MFMAs per iter) ----
    int jb = w << 6;
    const uint4* PTb = PTt + (size_t)b*16384;
    const uint4* Kb  = Kt  + (size_t)b*16384;
    f32x4 a00 = {0.f,0.f,0.f,0.f}, a01 = a00, a02 = a00, a03 = a00;
    f32x4 a10 = a00, a11 = a00, a12 = a00, a13 = a00;
    int j0 = jb + l15;
    half2v e00 = (half2v)(_Float16)distS[0][j0];
    half2v e01 = (half2v)(_Float16)distS[0][j0+16];
    half2v e02 = (half2v)(_Float16)distS[0][j0+32];
    half2v e03 = (half2v)(_Float16)distS[0][j0+48];
    half2v e10 = (half2v)(_Float16)distS[1][j0];
    half2v e11 = (half2v)(_Float16)distS[1][j0+16];
    half2v e12 = (half2v)(_Float16)distS[1][j0+32];
    half2v e13 = (half2v)(_Float16)distS[1][j0+48];
    int tbase = (w*4)*8;

    #pragma unroll
    for (int ks = 0; ks < 8; ks++){
        int cbase = ks*32 + lg*8;
        uint4 pt0 = PTb[(size_t)(tbase      + ks)*64 + l];
        uint4 pt1 = PTb[(size_t)(tbase + 8  + ks)*64 + l];
        uint4 pt2 = PTb[(size_t)(tbase + 16 + ks)*64 + l];
        uint4 pt3 = PTb[(size_t)(tbase + 24 + ks)*64 + l];
        uint4 k0 = Kb[(size_t)(tbase      + ks)*64 + l];
        uint4 k1 = Kb[(size_t)(tbase + 8  + ks)*64 + l];
        uint4 k2 = Kb[(size_t)(tbase + 16 + ks)*64 + l];
        uint4 k3 = Kb[(size_t)(tbase + 24 + ks)*64 + l];
        uint4 wfrag4 = w2f[ks][l];
        half8v wfrag; __builtin_memcpy(&wfrag, &wfrag4, 16);
        uint4 wd = *(uint4*)&w1dH[cbase >> 1];
        {
            uint4 bs = *(uint4*)&baseH[0][cbase >> 1];
            half8v f0 = build_afrag_h(pt0, bs, wd, e00);
            half8v f1 = build_afrag_h(pt1, bs, wd, e01);
            half8v f2 = build_afrag_h(pt2, bs, wd, e02);
            half8v f3 = build_afrag_h(pt3, bs, wd, e03);
            a00 = __builtin_amdgcn_mfma_f32_16x16x32_f16(f0, wfrag, a00, 0, 0, 0);
            a01 = __builtin_amdgcn_mfma_f32_16x16x32_f16(f1, wfrag, a01, 0, 0, 0);
            a02 = __builtin_amdgcn_mfma_f32_16x16x32_f16(f2, wfrag, a02, 0, 0, 0);
            a03 = __builtin_amdgcn_mfma_f32_16x16x32_f16(f3, wfrag, a03, 0, 0, 0);
        }
        {
            uint4 bs = *(uint4*)&baseH[1][cbase >> 1];
            half8v f0 = build_afrag_h(pt0, bs, wd, e10);
            half8v f1 = build_afrag_h(pt1, bs, wd, e11);
            half8v f2 = build_afrag_h(pt2, bs, wd, e12);
            half8v f3 = build_afrag_h(pt3, bs, wd, e13);
            a10 = __builtin_amdgcn_mfma_f32_16x16x32_f16(f0, wfrag, a10, 0, 0, 0);
            a11 = __builtin_amdgcn_mfma_f32_16x16x32_f16(f1, wfrag, a11, 0, 0, 0);
            a12 = __builtin_amdgcn_mfma_f32_16x16x32_f16(f2, wfrag, a12, 0, 0, 0);
            a13 = __builtin_amdgcn_mfma_f32_16x16x32_f16(f3, wfrag, a13, 0, 0, 0);
        }
        {
            short8v q0f = (l15 == ks) ? qreg0 : zero8;
            short8v q1f = (l15 == ks) ? qreg1 : zero8;
            short8v kf0 = *(short8v*)&k0, kf1 = *(short8v*)&k1, kf2 = *(short8v*)&k2, kf3 = *(short8v*)&k3;
            a00 = __builtin_amdgcn_mfma_f32_16x16x32_bf16(kf0, q0f, a00, 0, 0, 0);
            a01 = __builtin_amdgcn_mfma_f32_16x16x32_bf16(kf1, q0f, a01, 0, 0, 0);
            a02 = __builtin_amdgcn_mfma_f32_16x16x32_bf16(kf2, q0f, a02, 0, 0, 0);
            a03 = __builtin_amdgcn_mfma_f32_16x16x32_bf16(kf3, q0f, a03, 0, 0, 0);
            a10 = __builtin_amdgcn_mfma_f32_16x16x32_bf16(kf0, q1f, a10, 0, 0, 0);
            a11 = __builtin_amdgcn_mfma_f32_16x16x32_bf16(kf1, q1f, a11, 0, 0, 0);
            a12 = __builtin_amdgcn_mfma_f32_16x16x32_bf16(kf2, q1f, a12, 0, 0, 0);
            a13 = __builtin_amdgcn_mfma_f32_16x16x32_bf16(kf3, q1f, a13, 0, 0, 0);
        }
    }

    // ---- write logits (f16): D layout col=lane&15 (=h), row=(lane>>4)*4+r ----
    if (l15 < 8){
        float b2h = b2S[l15];
        ushort_t neg = f2h_u(-1e9f);
        #pragma unroll
        for (int r = 0; r < 4; r++){
            int jr0 = jb +  0 + lg*4 + r;
            int jr1 = jb + 16 + lg*4 + r;
            int jr2 = jb + 32 + lg*4 + r;
            int jr3 = jb + 48 + lg*4 + r;
            Ls[0][l15][jr0] = mS[jr0] ? f2h_u(a00[r] + b2h) : neg;
            Ls[0][l15][jr1] = mS[jr1] ? f2h_u(a01[r] + b2h) : neg;
            Ls[0][l15][jr2] = mS[jr2] ? f2h_u(a02[r] + b2h) : neg;
            Ls[0][l15][jr3] = mS[jr3] ? f2h_u(a03[r] + b2h) : neg;
            Ls[1][l15][jr0] = mS[jr0] ? f2h_u(a10[r] + b2h) : neg;
            Ls[1][l15][jr1] = mS[jr1] ? f2h_u(a11[r] + b2h) : neg;
            Ls[1][l15][jr2] = mS[jr2] ? f2h_u(a12[r] + b2h) : neg;
            Ls[1][l15][jr3] = mS[jr3] ? f2h_u(a13[r] + b2h) : neg;
        }
    }
    __syncthreads();

    // ---- softmax: 16 groups (q,h) x 32 lanes, barrier-free shfl reductions ----
    {
        int g = tid >> 5, lane = tid & 31;
        int sq = g >> 3, shh = g & 7;
        ushort_t* Li = &Ls[sq][shh][0];
        float m = -3e38f;
        for (int jj = lane; jj < N_; jj += 32) m = fmaxf(m, h2f_u(Li[jj]));
        #pragma unroll
        for (int s = 16; s > 0; s >>= 1) m = fmaxf(m, __shfl_xor(m, s, 32));
        float ss = 0.f;
        for (int jj = lane; jj < N_; jj += 32){
            float e = __expf(h2f_u(Li[jj]) - m);
            ushort_t us = f2h_u(e);
            Li[jj] = us;
            ss += h2f_u(us);
        }
        #pragma unroll
        for (int s = 16; s > 0; s >>= 1) ss += __shfl_xor(ss, s, 32);
        if (lane == 0) inv_s[sq][shh] = 1.0f / ss;
    }
    __syncthreads();

    // ---- PV: f16 dot2 against V^T rows, 4-way ILP ----
    {
        int q = tid >> 8, d = tid & 255, hh = d >> 5;
        const unsigned int* vtrow = (const unsigned int*)(VTf + (size_t)(b*E_ + d)*N_);
        const uint4* vp = (const uint4*)vtrow;
        const uint4* Lp = (const uint4*)&Ls[q][hh][0];
        float o0 = 0.f, o1 = 0.f, o2 = 0.f, o3 = 0.f;
        #pragma unroll 2
        for (int t2 = 0; t2 < N_/8; t2 += 4){
            uint4 v0 = vp[t2], v1 = vp[t2+1], v2 = vp[t2+2], v3 = vp[t2+3];
            uint4 p0 = Lp[t2], p1 = Lp[t2+1], p2 = Lp[t2+2], p3 = Lp[t2+3];
            o0 = dot2h(p0.x, v0.x, o0); o0 = dot2h(p0.y, v0.y, o0);
            o0 = dot2h(p0.z, v0.z, o0); o0 = dot2h(p0.w, v0.w, o0);
            o1 = dot2h(p1.x, v1.x, o1); o1 = dot2h(p1.y, v1.y, o1);
            o1 = dot2h(p1.z, v1.z, o1); o1 = dot2h(p1.w, v1.w, o1);
            o2 = dot2h(p2.x, v2.x, o2); o2 = dot2h(p2.y, v2.y, o2);
            o2 = dot2h(p2.z, v2.z, o2); o2 = dot2h(p2.w, v2.w, o2);
            o3 = dot2h(p3.x, v3.x, o3); o3 = dot2h(p3.y, v3.y, o3);
            o3 = dot2h(p3.z, v3.z, o3); o3 = dot2h(p3.w, v3.w, o3);
        }
        float o = (o0 + o1) + (o2 + o3);
        attnob[(size_t)(b*N_ + i0 + q)*E_ + d] = f2bf_rne(o * inv_s[q][hh]);
    }
}

// ---------------- residual + LayerNorm (dual output) ----------------
__global__ __launch_bounds__(256) void ln_add_kernel(const float* __restrict__ a,
        const float* __restrict__ bsrc, const float* __restrict__ s,
        const float* __restrict__ bb, float* __restrict__ out,
        ushort_t* __restrict__ outb){
    int row = blockIdx.x, e = threadIdx.x;
    float v = a[(size_t)row*E_ + e] + bsrc[(size_t)row*E_ + e];
    __shared__ float red[256];
    red[e] = v; __syncthreads();
    for (int t = 128; t > 0; t >>= 1){ if (e < t) red[e] += red[e+t]; __syncthreads(); }
    float m = red[0] * (1.0f/E_); __syncthreads();
    float d = v - m;
    red[e] = d*d; __syncthreads();
    for (int t = 128; t > 0; t >>= 1){ if (e < t) red[e] += red[e+t]; __syncthreads(); }
    float var = red[0] * (1.0f/E_);
    float o = d * rsqrtf(var + 1e-5f) * s[e] + bb[e];
    out[(size_t)row*E_ + e] = o;
    outb[(size_t)row*E_ + e] = f2bf_rne(o);
}

// ---------------- masked pooling ----------------
__global__ __launch_bounds__(256) void pool_kernel(const float* __restrict__ feat,
        const int* __restrict__ maskI, float* __restrict__ pooled){
    int b = blockIdx.x, e = threadIdx.x;
    __shared__ int ml[N_];
    for (int n = e; n < N_; n += 256) ml[n] = maskI[b*N_ + n];
    __syncthreads();
    float s = 0.f, mx = -1e30f; int cnt = 0;
    for (int n = 0; n < N_; n++){
        if (ml[n]){
            float v = feat[(size_t)(b*N_ + n)*E_ + e];
            s += v; mx = fmaxf(mx, v); cnt++;
        }
    }
    float mean = s / ((float)cnt + 1e-6f);
    if (cnt == 0) mx = mean;
    pooled[b*768 + e]       = mx;
    pooled[b*768 + 256 + e] = mean;
}

// ---------------- params MLP ----------------
__global__ __launch_bounds__(256) void pf_kernel(const float* __restrict__ params,
        const float* __restrict__ w1, const float* __restrict__ b1,
        const float* __restrict__ lns, const float* __restrict__ lnb,
        const float* __restrict__ w2, const float* __restrict__ b2,
        float* __restrict__ pooled){
    int b = blockIdx.x, e = threadIdx.x;
    __shared__ float red[256];
    __shared__ float pfn[256];
    float p0 = params[b*5+0], p1 = params[b*5+1], p2 = params[b*5+2], p3 = params[b*5+3], p4 = params[b*5+4];
    float t = b1[e] + p0*w1[e] + p1*w1[E_+e] + p2*w1[2*E_+e] + p3*w1[3*E_+e] + p4*w1[4*E_+e];
    t = gelu_f(t);
    red[e] = t; __syncthreads();
    for (int s = 128; s > 0; s >>= 1){ if (e < s) red[e] += red[e+s]; __syncthreads(); }
    float m = red[0] * (1.0f/E_); __syncthreads();
    float d = t - m;
    red[e] = d*d; __syncthreads();
    for (int s = 128; s > 0; s >>= 1){ if (e < s) red[e] += red[e+s]; __syncthreads(); }
    float v = red[0] * (1.0f/E_);
    pfn[e] = d * rsqrtf(v + 1e-5f) * lns[e] + lnb[e];
    __syncthreads();
    float u = b2[e];
    for (int c = 0; c < E_; c++) u += pfn[c] * w2[c*E_ + e];
    pooled[b*768 + 512 + e] = gelu_f(u);
}

// ---------------- classifier head ----------------
__global__ __launch_bounds__(512) void cls_kernel(const float* __restrict__ pooled,
        const float* __restrict__ w1, const float* __restrict__ b1,
        const float* __restrict__ w2, const float* __restrict__ b2,
        const float* __restrict__ w3, const float* __restrict__ b3,
        float* __restrict__ out){
    int b = blockIdx.x, t = threadIdx.x;
    __shared__ float hb[768];
    __shared__ float h1[512];
    __shared__ float h2[256];
    for (int idx = t; idx < 768; idx += 512) hb[idx] = pooled[b*768 + idx];
    __syncthreads();
    float a = b1[t];
    for (int c = 0; c < 768; c++) a += hb[c] * w1[c*512 + t];
    h1[t] = gelu_f(a);
    __syncthreads();
    if (t < 256){
        float a2 = b2[t];
        for (int c = 0; c < 512; c++) a2 += h1[c] * w2[c*256 + t];
        h2[t] = gelu_f(a2);
    }
    __syncthreads();
    if (t < 2){
        float a3 = b3[t];
        for (int c = 0; c < 256; c++) a3 += h2[c] * w3[c*2 + t];
        out[b*2 + t] = a3;
    }
}

extern "C" void kernel_launch(void* const* d_in, const int* in_sizes, int n_in,
                              void* d_out, int out_size, void* d_ws, size_t ws_size,
                              hipStream_t stream){
    enum { I_HITS=0, I_MASK=1, I_PARAMS=2, I_EMBED_W=3, I_EMBED_B=4, I_ELN_S=5, I_ELN_B=6,
           I_POS_W=7, I_POS_B=8, I_QKV_W=9, I_OUT_W=10, I_OUT_B=11, I_PW1=12, I_PB1=13,
           I_PW2=14, I_PB2=15, I_FW1=16, I_FB1=17, I_FW2=18, I_FB2=19, I_N1S=20, I_N1B=21,
           I_N2S=22, I_N2B=23, I_PFW1=24, I_PFB1=25, I_PFLS=26, I_PFLB=27, I_PFW2=28, I_PFB2=29,
           I_CW1=30, I_CB1=31, I_CW2=32, I_CB2=33, I_CW3=34, I_CB3=35 };
    (void)n_in; (void)out_size; (void)ws_size;

    float* wsf = (float*)d_ws;
    int* maskI = (int*)d_ws;
    int* flag  = (int*)d_ws + 8192;
    size_t off = 8448;

    CvtTable tbl;
    float* cv[36];
    for (int idx = 0; idx < 36; idx++){
        if (idx == I_MASK){ cv[idx] = nullptr; tbl.src[idx] = d_in[idx]; tbl.dstoff[idx] = 0; continue; }
        cv[idx] = wsf + off;
        tbl.src[idx] = d_in[idx];
        tbl.dstoff[idx] = (int)off;
        off += (size_t)in_sizes[idx];
        off = (off + 3) & ~(size_t)3;
    }
    {
        int c2 = 0;
        for (int idx = 0; idx < 36; idx++){
            tbl.off[idx] = c2;
            if (idx != I_MASK) c2 += in_sizes[idx];
        }
        tbl.off[36] = c2;
    }

    float* feat  = wsf + off; off += (size_t)B_*N_*E_;
    float* qkv   = wsf + off; off += (size_t)B_*N_*3*E_;
    float* xbuf  = wsf + off; off += (size_t)B_*N_*E_;
    float* tmp   = wsf + off; off += (size_t)B_*N_*E_;
    float* ppart = wsf + off; off += (size_t)B_*32*6;
    float* pscale= wsf + off; off += (size_t)B_*6 + 2;
    float* pooled= wsf + off; off += (size_t)B_*768;
    ushort_t* featb  = (ushort_t*)(wsf + off); off += (size_t)B_*N_*E_/2;
    ushort_t* xbufb  = (ushort_t*)(wsf + off); off += (size_t)B_*N_*E_/2;
    ushort_t* attnob = (ushort_t*)(wsf + off); off += (size_t)B_*N_*E_/2;
    ushort_t* ffnhb  = (ushort_t*)(wsf + off); off += (size_t)B_*N_*DFF_/2;
    ushort_t* VTf    = (ushort_t*)(wsf + off); off += (size_t)B_*E_*N_/2;
    ushort_t* wtq = (ushort_t*)(wsf + off); off += (size_t)L_*768*E_/2;
    ushort_t* wto = (ushort_t*)(wsf + off); off += (size_t)L_*E_*E_/2;
    ushort_t* wt1 = (ushort_t*)(wsf + off); off += (size_t)L_*DFF_*E_/2;
    ushort_t* wt2 = (ushort_t*)(wsf + off); off += (size_t)L_*E_*DFF_/2;
    uint4* PTt = (uint4*)tmp;
    uint4* Kt  = PTt + (size_t)B_*16384;

    detect_and_mask<<<1, 256, 0, stream>>>((const unsigned int*)d_in[I_ELN_S], d_in[I_MASK], flag, maskI);
    {
        int total = tbl.off[36];
        cvt_all<<<(total + 255)/256, 256, 0, stream>>>(tbl, wsf, flag);
    }

    {
        TPTable tp;
        int t0 = 0;
        for (int l = 0; l < L_; l++){
            int m = l*4;
            tp.src[m+0] = cv[I_QKV_W] + (size_t)l*E_*3*E_; tp.dst[m+0] = wtq + (size_t)l*768*E_;
            tp.K[m+0] = E_;   tp.N[m+0] = 3*E_;
            tp.src[m+1] = cv[I_OUT_W] + (size_t)l*E_*E_;   tp.dst[m+1] = wto + (size_t)l*E_*E_;
            tp.K[m+1] = E_;   tp.N[m+1] = E_;
            tp.src[m+2] = cv[I_FW1] + (size_t)l*E_*DFF_;   tp.dst[m+2] = wt1 + (size_t)l*DFF_*E_;
            tp.K[m+2] = E_;   tp.N[m+2] = DFF_;
            tp.src[m+3] = cv[I_FW2] + (size_t)l*DFF_*E_;   tp.dst[m+3] = wt2 + (size_t)l*E_*DFF_;
            tp.K[m+3] = DFF_; tp.N[m+3] = E_;
        }
        for (int m = 0; m < 24; m++){
            tp.tile0[m] = t0;
            t0 += (tp.K[m] >> 5) * (tp.N[m] >> 5);
        }
        tp.tile0[24] = t0;
        wpack<<<t0, 256, 0, stream>>>(tp);
    }

    pair_stats<<<B_*32, 256, 0, stream>>>(cv[I_HITS], ppart);
    pair_fin<<<1, 128, 0, stream>>>(ppart, pscale);
    embed_kernel<<<B_*N_, 256, 0, stream>>>(cv[I_HITS], cv[I_EMBED_W], cv[I_EMBED_B],
                                            cv[I_ELN_S], cv[I_ELN_B], cv[I_POS_W], cv[I_POS_B],
                                            feat, featb);

    for (int l = 0; l < L_; l++){
        gemm_bf16<0><<<dim3(12,128), 256, 0, stream>>>(featb, wtq + (size_t)l*768*E_,
                                                       nullptr, qkv, nullptr, B_*N_, 3*E_, E_);
        pk_pack_tiled<<<B_*32, 512, 0, stream>>>(qkv, cv[I_HITS], pscale,
                                                 cv[I_PW1] + (size_t)l*6*E_, PTt, Kt);
        vT_pack<<<dim3(16,8,16), 256, 0, stream>>>(qkv, VTf);
        attn11_kernel<<<B_*(N_/2), 512, 0, stream>>>(qkv, PTt, Kt, VTf, cv[I_HITS], maskI, pscale,
                                               cv[I_PB1] + (size_t)l*E_,
                                               cv[I_PW1] + (size_t)l*6*E_,
                                               cv[I_PW2] + (size_t)l*E_*H_,
                                               cv[I_PB2] + (size_t)l*H_,
                                               attnob);
        gemm_bf16<0><<<dim3(4,128), 256, 0, stream>>>(attnob, wto + (size_t)l*E_*E_,
                                                      cv[I_OUT_B] + (size_t)l*E_, tmp, nullptr,
                                                      B_*N_, E_, E_);
        ln_add_kernel<<<B_*N_, 256, 0, stream>>>(feat, tmp, cv[I_N1S] + (size_t)l*E_,
                                                 cv[I_N1B] + (size_t)l*E_, xbuf, xbufb);
        gemm_bf16<1><<<dim3(16,128), 256, 0, stream>>>(xbufb, wt1 + (size_t)l*DFF_*E_,
                                                       cv[I_FB1] + (size_t)l*DFF_, nullptr, ffnhb,
                                                       B_*N_, DFF_, E_);
        gemm_bf16<0><<<dim3(4,128), 256, 0, stream>>>(ffnhb, wt2 + (size_t)l*E_*DFF_,
                                                      cv[I_FB2] + (size_t)l*E_, tmp, nullptr,
                                                      B_*N_, E_, DFF_);
        ln_add_kernel<<<B_*N_, 256, 0, stream>>>(xbuf, tmp, cv[I_N2S] + (size_t)l*E_,
                                                 cv[I_N2B] + (size_t)l*E_, feat, featb);
    }

    pool_kernel<<<B_, 256, 0, stream>>>(feat, maskI, pooled);
    pf_kernel<<<B_, 256, 0, stream>>>(cv[I_PARAMS], cv[I_PFW1], cv[I_PFB1],
                                      cv[I_PFLS], cv[I_PFLB], cv[I_PFW2], cv[I_PFB2], pooled);
    cls_kernel<<<B_, 512, 0, stream>>>(pooled, cv[I_CW1], cv[I_CB1], cv[I_CW2], cv[I_CB2],
                                       cv[I_CW3], cv[I_CB3], (float*)d_out);
}

// Round 18
// 2855.620 us; speedup vs baseline: 1.8609x; 1.0104x over previous
//
#include <hip/hip_runtime.h>
#include <hip/hip_bf16.h>
#include <hip/hip_fp16.h>

#define B_ 16
#define N_ 512
#define E_ 256
#define H_ 8
#define DH_ 32
#define L_ 6
#define DFF_ 1024
#define LSN 528

typedef unsigned short ushort_t;
typedef __attribute__((ext_vector_type(8))) short short8v;
typedef __attribute__((ext_vector_type(4))) float f32x4;
typedef __attribute__((ext_vector_type(2))) _Float16 half2v;
typedef __attribute__((ext_vector_type(8))) _Float16 half8v;

__device__ __forceinline__ float bf2f_raw(unsigned short u){
    unsigned int x = ((unsigned int)u) << 16; float f;
    __builtin_memcpy(&f, &x, 4); return f;
}
__device__ __forceinline__ unsigned short f2bf_rne(float f){
    unsigned int u; __builtin_memcpy(&u, &f, 4);
    u += 0x7fffu + ((u >> 16) & 1u);
    return (unsigned short)(u >> 16);
}
__device__ __forceinline__ unsigned int packbf2(float a, float b){
    return (unsigned int)f2bf_rne(a) | ((unsigned int)f2bf_rne(b) << 16);
}
__device__ __forceinline__ half2v u2hv(unsigned int u){ half2v h; __builtin_memcpy(&h, &u, 4); return h; }
__device__ __forceinline__ unsigned int hv2u(half2v h){ unsigned int u; __builtin_memcpy(&u, &h, 4); return u; }
__device__ __forceinline__ unsigned int pack2h(float a, float b){
    half2v h; h.x = (_Float16)a; h.y = (_Float16)b; return hv2u(h);
}
__device__ __forceinline__ ushort_t f2h_u(float f){
    _Float16 h = (_Float16)f; ushort_t u; __builtin_memcpy(&u, &h, 2); return u;
}
__device__ __forceinline__ float h2f_u(ushort_t u){
    _Float16 h; __builtin_memcpy(&h, &u, 2); return (float)h;
}
__device__ __forceinline__ float dot2h(unsigned int p, unsigned int v, float c){
#if __has_builtin(__builtin_amdgcn_fdot2)
    return __builtin_amdgcn_fdot2(u2hv(p), u2hv(v), c, false);
#else
    half2v a = u2hv(p), b = u2hv(v);
    return fmaf((float)a.y, (float)b.y, fmaf((float)a.x, (float)b.x, c));
#endif
}
__device__ __forceinline__ float gelu_f(float x){
    return 0.5f * x * (1.0f + erff(x * 0.7071067811865476f));
}

// ---------------- input normalization ----------------
__global__ void detect_and_mask(const unsigned int* __restrict__ lnS_raw,
                                const void* __restrict__ mask_raw,
                                int* __restrict__ flag, int* __restrict__ maskI){
    __shared__ int s_isbf, s_m32;
    if (threadIdx.x == 0){
        s_isbf = (lnS_raw[0] == 0x3F803F80u) ? 1 : 0;
        const unsigned int* mw = (const unsigned int*)mask_raw;
        int ok = 1;
        for (int k = 0; k < 64; k++){ if (mw[k] > 1u){ ok = 0; break; } }
        s_m32 = ok;
        *flag = s_isbf;
    }
    __syncthreads();
    if (s_m32){
        const int* mi = (const int*)mask_raw;
        for (int i = threadIdx.x; i < B_*N_; i += blockDim.x) maskI[i] = (mi[i] != 0);
    } else {
        const unsigned char* mb = (const unsigned char*)mask_raw;
        for (int i = threadIdx.x; i < B_*N_; i += blockDim.x) maskI[i] = (mb[i] != 0);
    }
}

struct CvtTable {
    const void* src[36];
    int off[37];
    int dstoff[36];
};

__global__ __launch_bounds__(256) void cvt_all(CvtTable t, float* __restrict__ base,
                                               const int* __restrict__ flag){
    int gi = blockIdx.x * 256 + threadIdx.x;
    if (gi >= t.off[36]) return;
    int seg = 0;
    for (int s = 1; s < 36; s++) if (gi >= t.off[s]) seg = s;
    int loc = gi - t.off[seg];
    float* dst = base + t.dstoff[seg] + loc;
    if (*flag) *dst = bf2f_raw(((const unsigned short*)t.src[seg])[loc]);
    else       *dst = ((const float*)t.src[seg])[loc];
}

// ---------------- weight transpose-pack: f32 [K][N] -> bf16 [N][K] ----------------
struct TPTable {
    const float* src[24];
    ushort_t* dst[24];
    int K[24], N[24];
    int tile0[25];
};

__global__ __launch_bounds__(256) void wpack(TPTable tp){
    int bid = blockIdx.x;
    int m = 0;
    while (m + 1 < 24 && bid >= tp.tile0[m+1]) m++;
    int t = bid - tp.tile0[m];
    int tiles_n = tp.N[m] >> 5;
    int tk = t / tiles_n, tn = t - tk*tiles_n;
    __shared__ float tile[32][33];
    int tx = threadIdx.x & 31, ty = threadIdx.x >> 5;
    const float* src = tp.src[m];
    int Nn = tp.N[m], Kk = tp.K[m];
    #pragma unroll
    for (int r = 0; r < 4; r++){
        int k = tk*32 + ty + r*8;
        tile[ty + r*8][tx] = src[(size_t)k*Nn + tn*32 + tx];
    }
    __syncthreads();
    ushort_t* dst = tp.dst[m];
    #pragma unroll
    for (int r = 0; r < 4; r++){
        int n = tn*32 + ty + r*8;
        dst[(size_t)n*Kk + tk*32 + tx] = f2bf_rne(tile[tx][ty + r*8]);
    }
}

// ---------------- pair-feature normalization stats ----------------
__global__ __launch_bounds__(256) void pair_stats(const float* __restrict__ hits,
                                                  float* __restrict__ ppart){
    int blk = blockIdx.x;
    int b = blk >> 5, chunk = blk & 31;
    int tid = threadIdx.x;
    float acc[6] = {0,0,0,0,0,0};
    for (int ii = 0; ii < 16; ii++){
        int i = chunk*16 + ii;
        const float* hi = hits + (size_t)(b*N_ + i)*5;
        float h0=hi[0], h1=hi[1], h2=hi[2], h3=hi[3], h4=hi[4];
        for (int j = tid; j < N_; j += 256){
            const float* hj = hits + (size_t)(b*N_ + j)*5;
            float dx = h0 - hj[0], dy = h1 - hj[1];
            acc[0] += fabsf(dx);
            acc[1] += fabsf(dy);
            acc[2] += sqrtf(dx*dx + dy*dy + 1e-6f);
            acc[3] += fabsf(h2 - hj[2]);
            acc[4] += fabsf(h3 - hj[3]);
            acc[5] += fabsf(h4 - hj[4]);
        }
    }
    __shared__ float red[256];
    for (int c = 0; c < 6; c++){
        red[tid] = acc[c]; __syncthreads();
        for (int s = 128; s > 0; s >>= 1){ if (tid < s) red[tid] += red[tid+s]; __syncthreads(); }
        if (tid == 0) ppart[(size_t)(b*32 + chunk)*6 + c] = red[0];
        __syncthreads();
    }
}

__global__ void pair_fin(const float* __restrict__ ppart, float* __restrict__ pscale){
    int t = threadIdx.x;
    if (t >= B_*6) return;
    int b = t / 6, c = t % 6;
    float s = 0.f;
    for (int k = 0; k < 32; k++) s += ppart[(size_t)(b*32 + k)*6 + c];
    float mean = s * (1.0f / (float)(N_*N_));
    pscale[t] = 1.0f / (mean + 1e-6f);
}

// ---------------- embedding (dual f32+bf16 output, shfl reductions) ----------------
__global__ __launch_bounds__(256) void embed_kernel(const float* __restrict__ hits,
        const float* __restrict__ ew, const float* __restrict__ eb,
        const float* __restrict__ lns, const float* __restrict__ lnb,
        const float* __restrict__ pw, const float* __restrict__ pb,
        float* __restrict__ feat, ushort_t* __restrict__ featb){
    int row = blockIdx.x; int e = threadIdx.x;
    int lane = e & 63, wid = e >> 6;
    const float* h = hits + (size_t)row*5;
    float h0=h[0], h1=h[1], h2=h[2], h3=h[3], h4=h[4];
    float t = eb[e] + h0*ew[e] + h1*ew[E_+e] + h2*ew[2*E_+e] + h3*ew[3*E_+e] + h4*ew[4*E_+e];
    __shared__ float w8[8];
    float s = t;
    #pragma unroll
    for (int off = 32; off; off >>= 1) s += __shfl_xor(s, off, 64);
    if (lane == 0) w8[wid] = s;
    __syncthreads();
    float m = (w8[0]+w8[1]+w8[2]+w8[3]) * (1.0f/E_);
    float d = t - m;
    float s2 = d*d;
    #pragma unroll
    for (int off = 32; off; off >>= 1) s2 += __shfl_xor(s2, off, 64);
    if (lane == 0) w8[4+wid] = s2;
    __syncthreads();
    float v = (w8[4]+w8[5]+w8[6]+w8[7]) * (1.0f/E_);
    float ln = d * rsqrtf(v + 1e-5f) * lns[e] + lnb[e];
    float g1 = gelu_f(ln);
    float p = pb[e] + h0*pw[e] + h1*pw[E_+e];
    float o = g1 + gelu_f(p);
    feat[(size_t)row*E_ + e] = o;
    featb[(size_t)row*E_ + e] = f2bf_rne(o);
}

// ---------------- bf16 MFMA GEMM ----------------
template<int ACT>
__global__ __launch_bounds__(256) void gemm_bf16(const ushort_t* __restrict__ A,
        const ushort_t* __restrict__ WT, const float* __restrict__ bias,
        float* __restrict__ C, ushort_t* __restrict__ Cbf, int M, int Ncols, int K){
    __shared__ __align__(16) ushort_t As[64][72];
    __shared__ __align__(16) ushort_t Bs[64][72];
    int tid = threadIdx.x;
    int mBase = blockIdx.y * 64, nBase = blockIdx.x * 64;
    int l = tid & 63, w = tid >> 6;
    int l15 = l & 15, lg = l >> 4;
    int wm = w >> 1, wn = w & 1;
    int srow = tid >> 2, skq = (tid & 3) * 16;
    f32x4 acc00 = {0.f,0.f,0.f,0.f}, acc01 = acc00, acc10 = acc00, acc11 = acc00;
    for (int kt = 0; kt < K; kt += 64){
        uint4 av0 = *(const uint4*)(A  + (size_t)(mBase+srow)*K + kt + skq);
        uint4 av1 = *(const uint4*)(A  + (size_t)(mBase+srow)*K + kt + skq + 8);
        uint4 bv0 = *(const uint4*)(WT + (size_t)(nBase+srow)*K + kt + skq);
        uint4 bv1 = *(const uint4*)(WT + (size_t)(nBase+srow)*K + kt + skq + 8);
        *(uint4*)&As[srow][skq]     = av0;
        *(uint4*)&As[srow][skq + 8] = av1;
        *(uint4*)&Bs[srow][skq]     = bv0;
        *(uint4*)&Bs[srow][skq + 8] = bv1;
        __syncthreads();
        #pragma unroll
        for (int ks = 0; ks < 2; ks++){
            short8v a0 = *(short8v*)&As[wm*32      + l15][ks*32 + lg*8];
            short8v a1 = *(short8v*)&As[wm*32 + 16 + l15][ks*32 + lg*8];
            short8v b0 = *(short8v*)&Bs[wn*32      + l15][ks*32 + lg*8];
            short8v b1 = *(short8v*)&Bs[wn*32 + 16 + l15][ks*32 + lg*8];
            acc00 = __builtin_amdgcn_mfma_f32_16x16x32_bf16(a0, b0, acc00, 0, 0, 0);
            acc01 = __builtin_amdgcn_mfma_f32_16x16x32_bf16(a0, b1, acc01, 0, 0, 0);
            acc10 = __builtin_amdgcn_mfma_f32_16x16x32_bf16(a1, b0, acc10, 0, 0, 0);
            acc11 = __builtin_amdgcn_mfma_f32_16x16x32_bf16(a1, b1, acc11, 0, 0, 0);
        }
        __syncthreads();
    }
    #pragma unroll
    for (int fm = 0; fm < 2; fm++){
        #pragma unroll
        for (int fn = 0; fn < 2; fn++){
            f32x4 a = (fm==0) ? ((fn==0)?acc00:acc01) : ((fn==0)?acc10:acc11);
            int col = nBase + wn*32 + fn*16 + l15;
            float bs = bias ? bias[col] : 0.f;
            #pragma unroll
            for (int r = 0; r < 4; r++){
                int row = mBase + wm*32 + fm*16 + lg*4 + r;
                float o = a[r] + bs;
                if (ACT == 1) o = gelu_f(o);
                if (C)   C[(size_t)row*Ncols + col] = o;
                if (Cbf) Cbf[(size_t)row*Ncols + col] = f2bf_rne(o);
            }
        }
    }
}

// ---------------- fused per-layer prepack: PK tiles + V transpose ----------------
__global__ __launch_bounds__(512) void pkv_pack(const float* __restrict__ qkv,
        const float* __restrict__ hits, const float* __restrict__ pscale,
        const float* __restrict__ w1, uint4* __restrict__ PTt, uint4* __restrict__ Kt,
        ushort_t* __restrict__ VTf){
    int blk = blockIdx.x;               // b*32 + jb16
    int b = blk >> 5;
    int jb16 = blk & 31;
    int tid = threadIdx.x;
    // ---- PK tiles (no LDS, no barrier) ----
    {
        int ks = tid >> 6, l = tid & 63, l15 = l & 15, lg = l >> 4;
        int n = jb16*16 + l15;
        int row = b*N_ + n;
        const float* sc6 = pscale + b*6;
        const float* h = hits + (size_t)row*5;
        float a0 = h[0]*sc6[0], a1 = h[1]*sc6[1], a2 = h[2]*sc6[3], a3 = h[3]*sc6[4], a4 = h[4]*sc6[5];
        int c0 = ks*32 + lg*8;
        float p[8];
        #pragma unroll
        for (int e = 0; e < 8; e++){
            int c = c0 + e;
            p[e] = a0*w1[c] + a1*w1[E_+c] + a2*w1[3*E_+c] + a3*w1[4*E_+c] + a4*w1[5*E_+c];
        }
        uint4 up;
        up.x = pack2h(p[0], p[1]); up.y = pack2h(p[2], p[3]);
        up.z = pack2h(p[4], p[5]); up.w = pack2h(p[6], p[7]);
        const float* kr = qkv + (size_t)row*768 + 256 + c0;
        uint4 uk;
        uk.x = packbf2(kr[0], kr[1]); uk.y = packbf2(kr[2], kr[3]);
        uk.z = packbf2(kr[4], kr[5]); uk.w = packbf2(kr[6], kr[7]);
        size_t idx = ((size_t)blk*8 + ks)*64 + l;
        PTt[idx] = up;
        Kt[idx]  = uk;
    }
    // ---- V transpose (LDS-staged) ----
    __shared__ float vt[16][257];
    for (int idx = tid; idx < 4096; idx += 512){
        int n = idx >> 8, d = idx & 255;
        vt[n][d] = qkv[(size_t)(b*N_ + jb16*16 + n)*768 + 512 + d];
    }
    __syncthreads();
    for (int idx = tid; idx < 4096; idx += 512){
        int d = idx >> 4, n = idx & 15;
        VTf[(size_t)(b*E_ + d)*N_ + jb16*16 + n] = f2h_u(vt[n][d]);
    }
}

// ---------------- A-fragment build (packed f16 native ops): max(bs - p + d*wd, 0) --------
__device__ __forceinline__ half8v build_afrag_h(uint4 pt, uint4 bs, uint4 wd, half2v d2){
    half2v z2 = (half2v)(_Float16)0;
    half2v r0 = d2 * u2hv(wd.x) + (u2hv(bs.x) - u2hv(pt.x));
    half2v r1 = d2 * u2hv(wd.y) + (u2hv(bs.y) - u2hv(pt.y));
    half2v r2 = d2 * u2hv(wd.z) + (u2hv(bs.z) - u2hv(pt.z));
    half2v r3 = d2 * u2hv(wd.w) + (u2hv(bs.w) - u2hv(pt.w));
    r0 = __builtin_elementwise_max(r0, z2);
    r1 = __builtin_elementwise_max(r1, z2);
    r2 = __builtin_elementwise_max(r2, z2);
    r3 = __builtin_elementwise_max(r3, z2);
    uint4 u;
    u.x = hv2u(r0); u.y = hv2u(r1); u.z = hv2u(r2); u.w = hv2u(r3);
    half8v r; __builtin_memcpy(&r, &u, 16); return r;
}

// ---------------- fused attention v11 (best known): merged ks-loop, shfl softmax, ILP PV ----
__global__ __launch_bounds__(512, 4) void attn11_kernel(
        const float* __restrict__ qkv, const uint4* __restrict__ PTt,
        const uint4* __restrict__ Kt, const ushort_t* __restrict__ VTf,
        const float* __restrict__ hits,
        const int* __restrict__ maskI, const float* __restrict__ pscale,
        const float* __restrict__ b1, const float* __restrict__ w1,
        const float* __restrict__ w2, const float* __restrict__ b2,
        ushort_t* __restrict__ attnob){
    __shared__ __align__(16) ushort_t Ls[2][H_][LSN];
    __shared__ __align__(16) uint4 w2f[8][64];
    __shared__ __align__(16) unsigned int baseH[2][128];
    __shared__ __align__(16) unsigned int w1dH[128];
    __shared__ float distS[2][N_];
    __shared__ unsigned char mS[N_];
    __shared__ float b2S[8];
    __shared__ float inv_s[2][H_];

    int bid = blockIdx.x;
    int x = bid & 7, k = bid >> 3;
    int b = 2*x + (k >> 8);
    int i0 = (k & 255) * 2;
    int tid = threadIdx.x;
    int l = tid & 63, w = tid >> 6;
    int l15 = l & 15, lg = l >> 4;
    const float scale = 0.17677669529663687f;

    if (tid < 256){
        int q = tid >> 7, cp = tid & 127;
        int c = cp*2;
        const float* sc6 = pscale + b*6;
        const float* hr = hits + (size_t)(b*N_ + i0 + q)*5;
        float pa = hr[0]*sc6[0]*w1[c] + hr[1]*sc6[1]*w1[E_+c] + hr[2]*sc6[3]*w1[3*E_+c]
                 + hr[3]*sc6[4]*w1[4*E_+c] + hr[4]*sc6[5]*w1[5*E_+c] + b1[c];
        float pb2 = hr[0]*sc6[0]*w1[c+1] + hr[1]*sc6[1]*w1[E_+c+1] + hr[2]*sc6[3]*w1[3*E_+c+1]
                  + hr[3]*sc6[4]*w1[4*E_+c+1] + hr[4]*sc6[5]*w1[5*E_+c+1] + b1[c+1];
        baseH[q][cp] = pack2h(pa, pb2);
        if (tid < 128){
            float wa = sc6[2]*w1[2*E_ + c], wb = sc6[2]*w1[2*E_ + c + 1];
            w1dH[cp] = pack2h(wa, wb);
        }
        if (tid < 8) b2S[tid] = b2[tid];
    }
    {
        int ks = tid >> 6, lv = tid & 63;
        int h = lv & 15, g = lv >> 4;
        uint4 u = {0u,0u,0u,0u};
        if (h < 8){
            int cb = ks*32 + g*8;
            const float* wp = w2 + (size_t)cb*H_ + h;
            u.x = pack2h(wp[0*H_], wp[1*H_]);
            u.y = pack2h(wp[2*H_], wp[3*H_]);
            u.z = pack2h(wp[4*H_], wp[5*H_]);
            u.w = pack2h(wp[6*H_], wp[7*H_]);
        }
        w2f[ks][lv] = u;
    }
    for (int idx = tid; idx < 1024; idx += 512){
        int q = idx >> 9, j = idx & 511;
        const float* hi = hits + (size_t)(b*N_ + i0 + q)*5;
        const float* hj = hits + (size_t)(b*N_ + j)*5;
        float dx = hi[0] - hj[0], dy = hi[1] - hj[1];
        distS[q][j] = sqrtf(dx*dx + dy*dy + 1e-6f);
        if (q == 0) mS[j] = (unsigned char)(maskI[b*N_ + j] != 0);
    }
    uint4 qz = {0u,0u,0u,0u};
    short8v zero8 = *(short8v*)&qz;
    short8v qreg0 = zero8, qreg1 = zero8;
    if (l15 < 8){
        const float* Q0 = qkv + (size_t)(b*N_ + i0    )*768 + l15*32 + lg*8;
        const float* Q1 = qkv + (size_t)(b*N_ + i0 + 1)*768 + l15*32 + lg*8;
        uint4 u0, u1;
        u0.x = packbf2(Q0[0]*scale, Q0[1]*scale); u0.y = packbf2(Q0[2]*scale, Q0[3]*scale);
        u0.z = packbf2(Q0[4]*scale, Q0[5]*scale); u0.w = packbf2(Q0[6]*scale, Q0[7]*scale);
        u1.x = packbf2(Q1[0]*scale, Q1[1]*scale); u1.y = packbf2(Q1[2]*scale, Q1[3]*scale);
        u1.z = packbf2(Q1[4]*scale, Q1[5]*scale); u1.w = packbf2(Q1[6]*scale, Q1[7]*scale);
        qreg0 = *(short8v*)&u0; qreg1 = *(short8v*)&u1;
    }
    __syncthreads();

    int jb = w << 6;
    const uint4* PTb = PTt + (size_t)b*16384;
    const uint4* Kb  = Kt  + (size_t)b*16384;
    f32x4 a00 = {0.f,0.f,0.f,0.f}, a01 = a00, a02 = a00, a03 = a00;
    f32x4 a10 = a00, a11 = a00, a12 = a00, a13 = a00;
    int j0 = jb + l15;
    half2v e00 = (half2v)(_Float16)distS[0][j0];
    half2v e01 = (half2v)(_Float16)distS[0][j0+16];
    half2v e02 = (half2v)(_Float16)distS[0][j0+32];
    half2v e03 = (half2v)(_Float16)distS[0][j0+48];
    half2v e10 = (half2v)(_Float16)distS[1][j0];
    half2v e11 = (half2v)(_Float16)distS[1][j0+16];
    half2v e12 = (half2v)(_Float16)distS[1][j0+32];
    half2v e13 = (half2v)(_Float16)distS[1][j0+48];
    int tbase = (w*4)*8;

    #pragma unroll
    for (int ks = 0; ks < 8; ks++){
        int cbase = ks*32 + lg*8;
        uint4 pt0 = PTb[(size_t)(tbase      + ks)*64 + l];
        uint4 pt1 = PTb[(size_t)(tbase + 8  + ks)*64 + l];
        uint4 pt2 = PTb[(size_t)(tbase + 16 + ks)*64 + l];
        uint4 pt3 = PTb[(size_t)(tbase + 24 + ks)*64 + l];
        uint4 k0 = Kb[(size_t)(tbase      + ks)*64 + l];
        uint4 k1 = Kb[(size_t)(tbase + 8  + ks)*64 + l];
        uint4 k2 = Kb[(size_t)(tbase + 16 + ks)*64 + l];
        uint4 k3 = Kb[(size_t)(tbase + 24 + ks)*64 + l];
        uint4 wfrag4 = w2f[ks][l];
        half8v wfrag; __builtin_memcpy(&wfrag, &wfrag4, 16);
        uint4 wd = *(uint4*)&w1dH[cbase >> 1];
        {
            uint4 bs = *(uint4*)&baseH[0][cbase >> 1];
            half8v f0 = build_afrag_h(pt0, bs, wd, e00);
            half8v f1 = build_afrag_h(pt1, bs, wd, e01);
            half8v f2 = build_afrag_h(pt2, bs, wd, e02);
            half8v f3 = build_afrag_h(pt3, bs, wd, e03);
            a00 = __builtin_amdgcn_mfma_f32_16x16x32_f16(f0, wfrag, a00, 0, 0, 0);
            a01 = __builtin_amdgcn_mfma_f32_16x16x32_f16(f1, wfrag, a01, 0, 0, 0);
            a02 = __builtin_amdgcn_mfma_f32_16x16x32_f16(f2, wfrag, a02, 0, 0, 0);
            a03 = __builtin_amdgcn_mfma_f32_16x16x32_f16(f3, wfrag, a03, 0, 0, 0);
        }
        {
            uint4 bs = *(uint4*)&baseH[1][cbase >> 1];
            half8v f0 = build_afrag_h(pt0, bs, wd, e10);
            half8v f1 = build_afrag_h(pt1, bs, wd, e11);
            half8v f2 = build_afrag_h(pt2, bs, wd, e12);
            half8v f3 = build_afrag_h(pt3, bs, wd, e13);
            a10 = __builtin_amdgcn_mfma_f32_16x16x32_f16(f0, wfrag, a10, 0, 0, 0);
            a11 = __builtin_amdgcn_mfma_f32_16x16x32_f16(f1, wfrag, a11, 0, 0, 0);
            a12 = __builtin_amdgcn_mfma_f32_16x16x32_f16(f2, wfrag, a12, 0, 0, 0);
            a13 = __builtin_amdgcn_mfma_f32_16x16x32_f16(f3, wfrag, a13, 0, 0, 0);
        }
        {
            short8v q0f = (l15 == ks) ? qreg0 : zero8;
            short8v q1f = (l15 == ks) ? qreg1 : zero8;
            short8v kf0 = *(short8v*)&k0, kf1 = *(short8v*)&k1, kf2 = *(short8v*)&k2, kf3 = *(short8v*)&k3;
            a00 = __builtin_amdgcn_mfma_f32_16x16x32_bf16(kf0, q0f, a00, 0, 0, 0);
            a01 = __builtin_amdgcn_mfma_f32_16x16x32_bf16(kf1, q0f, a01, 0, 0, 0);
            a02 = __builtin_amdgcn_mfma_f32_16x16x32_bf16(kf2, q0f, a02, 0, 0, 0);
            a03 = __builtin_amdgcn_mfma_f32_16x16x32_bf16(kf3, q0f, a03, 0, 0, 0);
            a10 = __builtin_amdgcn_mfma_f32_16x16x32_bf16(kf0, q1f, a10, 0, 0, 0);
            a11 = __builtin_amdgcn_mfma_f32_16x16x32_bf16(kf1, q1f, a11, 0, 0, 0);
            a12 = __builtin_amdgcn_mfma_f32_16x16x32_bf16(kf2, q1f, a12, 0, 0, 0);
            a13 = __builtin_amdgcn_mfma_f32_16x16x32_bf16(kf3, q1f, a13, 0, 0, 0);
        }
    }

    if (l15 < 8){
        float b2h = b2S[l15];
        ushort_t neg = f2h_u(-1e9f);
        #pragma unroll
        for (int r = 0; r < 4; r++){
            int jr0 = jb +  0 + lg*4 + r;
            int jr1 = jb + 16 + lg*4 + r;
            int jr2 = jb + 32 + lg*4 + r;
            int jr3 = jb + 48 + lg*4 + r;
            Ls[0][l15][jr0] = mS[jr0] ? f2h_u(a00[r] + b2h) : neg;
            Ls[0][l15][jr1] = mS[jr1] ? f2h_u(a01[r] + b2h) : neg;
            Ls[0][l15][jr2] = mS[jr2] ? f2h_u(a02[r] + b2h) : neg;
            Ls[0][l15][jr3] = mS[jr3] ? f2h_u(a03[r] + b2h) : neg;
            Ls[1][l15][jr0] = mS[jr0] ? f2h_u(a10[r] + b2h) : neg;
            Ls[1][l15][jr1] = mS[jr1] ? f2h_u(a11[r] + b2h) : neg;
            Ls[1][l15][jr2] = mS[jr2] ? f2h_u(a12[r] + b2h) : neg;
            Ls[1][l15][jr3] = mS[jr3] ? f2h_u(a13[r] + b2h) : neg;
        }
    }
    __syncthreads();

    {
        int g = tid >> 5, lane = tid & 31;
        int sq = g >> 3, shh = g & 7;
        ushort_t* Li = &Ls[sq][shh][0];
        float m = -3e38f;
        for (int jj = lane; jj < N_; jj += 32) m = fmaxf(m, h2f_u(Li[jj]));
        #pragma unroll
        for (int s = 16; s > 0; s >>= 1) m = fmaxf(m, __shfl_xor(m, s, 32));
        float ss = 0.f;
        for (int jj = lane; jj < N_; jj += 32){
            float e = __expf(h2f_u(Li[jj]) - m);
            ushort_t us = f2h_u(e);
            Li[jj] = us;
            ss += h2f_u(us);
        }
        #pragma unroll
        for (int s = 16; s > 0; s >>= 1) ss += __shfl_xor(ss, s, 32);
        if (lane == 0) inv_s[sq][shh] = 1.0f / ss;
    }
    __syncthreads();

    {
        int q = tid >> 8, d = tid & 255, hh = d >> 5;
        const unsigned int* vtrow = (const unsigned int*)(VTf + (size_t)(b*E_ + d)*N_);
        const uint4* vp = (const uint4*)vtrow;
        const uint4* Lp = (const uint4*)&Ls[q][hh][0];
        float o0 = 0.f, o1 = 0.f, o2 = 0.f, o3 = 0.f;
        #pragma unroll 2
        for (int t2 = 0; t2 < N_/8; t2 += 4){
            uint4 v0 = vp[t2], v1 = vp[t2+1], v2 = vp[t2+2], v3 = vp[t2+3];
            uint4 p0 = Lp[t2], p1 = Lp[t2+1], p2 = Lp[t2+2], p3 = Lp[t2+3];
            o0 = dot2h(p0.x, v0.x, o0); o0 = dot2h(p0.y, v0.y, o0);
            o0 = dot2h(p0.z, v0.z, o0); o0 = dot2h(p0.w, v0.w, o0);
            o1 = dot2h(p1.x, v1.x, o1); o1 = dot2h(p1.y, v1.y, o1);
            o1 = dot2h(p1.z, v1.z, o1); o1 = dot2h(p1.w, v1.w, o1);
            o2 = dot2h(p2.x, v2.x, o2); o2 = dot2h(p2.y, v2.y, o2);
            o2 = dot2h(p2.z, v2.z, o2); o2 = dot2h(p2.w, v2.w, o2);
            o3 = dot2h(p3.x, v3.x, o3); o3 = dot2h(p3.y, v3.y, o3);
            o3 = dot2h(p3.z, v3.z, o3); o3 = dot2h(p3.w, v3.w, o3);
        }
        float o = (o0 + o1) + (o2 + o3);
        attnob[(size_t)(b*N_ + i0 + q)*E_ + d] = f2bf_rne(o * inv_s[q][hh]);
    }
}

// ---------------- residual + LayerNorm (dual output, shfl reductions) ----------------
__global__ __launch_bounds__(256) void ln_add_kernel(const float* __restrict__ a,
        const float* __restrict__ bsrc, const float* __restrict__ s,
        const float* __restrict__ bb, float* __restrict__ out,
        ushort_t* __restrict__ outb){
    int row = blockIdx.x, e = threadIdx.x;
    int lane = e & 63, wid = e >> 6;
    float v = a[(size_t)row*E_ + e] + bsrc[(size_t)row*E_ + e];
    __shared__ float w8[8];
    float sm = v;
    #pragma unroll
    for (int off = 32; off; off >>= 1) sm += __shfl_xor(sm, off, 64);
    if (lane == 0) w8[wid] = sm;
    __syncthreads();
    float m = (w8[0]+w8[1]+w8[2]+w8[3]) * (1.0f/E_);
    float d = v - m;
    float s2 = d*d;
    #pragma unroll
    for (int off = 32; off; off >>= 1) s2 += __shfl_xor(s2, off, 64);
    if (lane == 0) w8[4+wid] = s2;
    __syncthreads();
    float var = (w8[4]+w8[5]+w8[6]+w8[7]) * (1.0f/E_);
    float o = d * rsqrtf(var + 1e-5f) * s[e] + bb[e];
    out[(size_t)row*E_ + e] = o;
    outb[(size_t)row*E_ + e] = f2bf_rne(o);
}

// ---------------- masked pooling ----------------
__global__ __launch_bounds__(256) void pool_kernel(const float* __restrict__ feat,
        const int* __restrict__ maskI, float* __restrict__ pooled){
    int b = blockIdx.x, e = threadIdx.x;
    __shared__ int ml[N_];
    for (int n = e; n < N_; n += 256) ml[n] = maskI[b*N_ + n];
    __syncthreads();
    float s = 0.f, mx = -1e30f; int cnt = 0;
    for (int n = 0; n < N_; n++){
        if (ml[n]){
            float v = feat[(size_t)(b*N_ + n)*E_ + e];
            s += v; mx = fmaxf(mx, v); cnt++;
        }
    }
    float mean = s / ((float)cnt + 1e-6f);
    if (cnt == 0) mx = mean;
    pooled[b*768 + e]       = mx;
    pooled[b*768 + 256 + e] = mean;
}

// ---------------- params MLP ----------------
__global__ __launch_bounds__(256) void pf_kernel(const float* __restrict__ params,
        const float* __restrict__ w1, const float* __restrict__ b1,
        const float* __restrict__ lns, const float* __restrict__ lnb,
        const float* __restrict__ w2, const float* __restrict__ b2,
        float* __restrict__ pooled){
    int b = blockIdx.x, e = threadIdx.x;
    __shared__ float red[256];
    __shared__ float pfn[256];
    float p0 = params[b*5+0], p1 = params[b*5+1], p2 = params[b*5+2], p3 = params[b*5+3], p4 = params[b*5+4];
    float t = b1[e] + p0*w1[e] + p1*w1[E_+e] + p2*w1[2*E_+e] + p3*w1[3*E_+e] + p4*w1[4*E_+e];
    t = gelu_f(t);
    red[e] = t; __syncthreads();
    for (int s = 128; s > 0; s >>= 1){ if (e < s) red[e] += red[e+s]; __syncthreads(); }
    float m = red[0] * (1.0f/E_); __syncthreads();
    float d = t - m;
    red[e] = d*d; __syncthreads();
    for (int s = 128; s > 0; s >>= 1){ if (e < s) red[e] += red[e+s]; __syncthreads(); }
    float v = red[0] * (1.0f/E_);
    pfn[e] = d * rsqrtf(v + 1e-5f) * lns[e] + lnb[e];
    __syncthreads();
    float u = b2[e];
    for (int c = 0; c < E_; c++) u += pfn[c] * w2[c*E_ + e];
    pooled[b*768 + 512 + e] = gelu_f(u);
}

// ---------------- classifier head ----------------
__global__ __launch_bounds__(512) void cls_kernel(const float* __restrict__ pooled,
        const float* __restrict__ w1, const float* __restrict__ b1,
        const float* __restrict__ w2, const float* __restrict__ b2,
        const float* __restrict__ w3, const float* __restrict__ b3,
        float* __restrict__ out){
    int b = blockIdx.x, t = threadIdx.x;
    __shared__ float hb[768];
    __shared__ float h1[512];
    __shared__ float h2[256];
    for (int idx = t; idx < 768; idx += 512) hb[idx] = pooled[b*768 + idx];
    __syncthreads();
    float a = b1[t];
    for (int c = 0; c < 768; c++) a += hb[c] * w1[c*512 + t];
    h1[t] = gelu_f(a);
    __syncthreads();
    if (t < 256){
        float a2 = b2[t];
        for (int c = 0; c < 512; c++) a2 += h1[c] * w2[c*256 + t];
        h2[t] = gelu_f(a2);
    }
    __syncthreads();
    if (t < 2){
        float a3 = b3[t];
        for (int c = 0; c < 256; c++) a3 += h2[c] * w3[c*2 + t];
        out[b*2 + t] = a3;
    }
}

extern "C" void kernel_launch(void* const* d_in, const int* in_sizes, int n_in,
                              void* d_out, int out_size, void* d_ws, size_t ws_size,
                              hipStream_t stream){
    enum { I_HITS=0, I_MASK=1, I_PARAMS=2, I_EMBED_W=3, I_EMBED_B=4, I_ELN_S=5, I_ELN_B=6,
           I_POS_W=7, I_POS_B=8, I_QKV_W=9, I_OUT_W=10, I_OUT_B=11, I_PW1=12, I_PB1=13,
           I_PW2=14, I_PB2=15, I_FW1=16, I_FB1=17, I_FW2=18, I_FB2=19, I_N1S=20, I_N1B=21,
           I_N2S=22, I_N2B=23, I_PFW1=24, I_PFB1=25, I_PFLS=26, I_PFLB=27, I_PFW2=28, I_PFB2=29,
           I_CW1=30, I_CB1=31, I_CW2=32, I_CB2=33, I_CW3=34, I_CB3=35 };
    (void)n_in; (void)out_size; (void)ws_size;

    float* wsf = (float*)d_ws;
    int* maskI = (int*)d_ws;
    int* flag  = (int*)d_ws + 8192;
    size_t off = 8448;

    CvtTable tbl;
    float* cv[36];
    for (int idx = 0; idx < 36; idx++){
        if (idx == I_MASK){ cv[idx] = nullptr; tbl.src[idx] = d_in[idx]; tbl.dstoff[idx] = 0; continue; }
        cv[idx] = wsf + off;
        tbl.src[idx] = d_in[idx];
        tbl.dstoff[idx] = (int)off;
        off += (size_t)in_sizes[idx];
        off = (off + 3) & ~(size_t)3;
    }
    {
        int c2 = 0;
        for (int idx = 0; idx < 36; idx++){
            tbl.off[idx] = c2;
            if (idx != I_MASK) c2 += in_sizes[idx];
        }
        tbl.off[36] = c2;
    }

    float* feat  = wsf + off; off += (size_t)B_*N_*E_;
    float* qkv   = wsf + off; off += (size_t)B_*N_*3*E_;
    float* xbuf  = wsf + off; off += (size_t)B_*N_*E_;
    float* tmp   = wsf + off; off += (size_t)B_*N_*E_;
    float* ppart = wsf + off; off += (size_t)B_*32*6;
    float* pscale= wsf + off; off += (size_t)B_*6 + 2;
    float* pooled= wsf + off; off += (size_t)B_*768;
    ushort_t* featb  = (ushort_t*)(wsf + off); off += (size_t)B_*N_*E_/2;
    ushort_t* xbufb  = (ushort_t*)(wsf + off); off += (size_t)B_*N_*E_/2;
    ushort_t* attnob = (ushort_t*)(wsf + off); off += (size_t)B_*N_*E_/2;
    ushort_t* ffnhb  = (ushort_t*)(wsf + off); off += (size_t)B_*N_*DFF_/2;
    ushort_t* VTf    = (ushort_t*)(wsf + off); off += (size_t)B_*E_*N_/2;
    ushort_t* wtq = (ushort_t*)(wsf + off); off += (size_t)L_*768*E_/2;
    ushort_t* wto = (ushort_t*)(wsf + off); off += (size_t)L_*E_*E_/2;
    ushort_t* wt1 = (ushort_t*)(wsf + off); off += (size_t)L_*DFF_*E_/2;
    ushort_t* wt2 = (ushort_t*)(wsf + off); off += (size_t)L_*E_*DFF_/2;
    uint4* PTt = (uint4*)tmp;
    uint4* Kt  = PTt + (size_t)B_*16384;

    detect_and_mask<<<1, 256, 0, stream>>>((const unsigned int*)d_in[I_ELN_S], d_in[I_MASK], flag, maskI);
    {
        int total = tbl.off[36];
        cvt_all<<<(total + 255)/256, 256, 0, stream>>>(tbl, wsf, flag);
    }

    {
        TPTable tp;
        int t0 = 0;
        for (int l = 0; l < L_; l++){
            int m = l*4;
            tp.src[m+0] = cv[I_QKV_W] + (size_t)l*E_*3*E_; tp.dst[m+0] = wtq + (size_t)l*768*E_;
            tp.K[m+0] = E_;   tp.N[m+0] = 3*E_;
            tp.src[m+1] = cv[I_OUT_W] + (size_t)l*E_*E_;   tp.dst[m+1] = wto + (size_t)l*E_*E_;
            tp.K[m+1] = E_;   tp.N[m+1] = E_;
            tp.src[m+2] = cv[I_FW1] + (size_t)l*E_*DFF_;   tp.dst[m+2] = wt1 + (size_t)l*DFF_*E_;
            tp.K[m+2] = E_;   tp.N[m+2] = DFF_;
            tp.src[m+3] = cv[I_FW2] + (size_t)l*DFF_*E_;   tp.dst[m+3] = wt2 + (size_t)l*E_*DFF_;
            tp.K[m+3] = DFF_; tp.N[m+3] = E_;
        }
        for (int m = 0; m < 24; m++){
            tp.tile0[m] = t0;
            t0 += (tp.K[m] >> 5) * (tp.N[m] >> 5);
        }
        tp.tile0[24] = t0;
        wpack<<<t0, 256, 0, stream>>>(tp);
    }

    pair_stats<<<B_*32, 256, 0, stream>>>(cv[I_HITS], ppart);
    pair_fin<<<1, 128, 0, stream>>>(ppart, pscale);
    embed_kernel<<<B_*N_, 256, 0, stream>>>(cv[I_HITS], cv[I_EMBED_W], cv[I_EMBED_B],
                                            cv[I_ELN_S], cv[I_ELN_B], cv[I_POS_W], cv[I_POS_B],
                                            feat, featb);

    for (int l = 0; l < L_; l++){
        gemm_bf16<0><<<dim3(12,128), 256, 0, stream>>>(featb, wtq + (size_t)l*768*E_,
                                                       nullptr, qkv, nullptr, B_*N_, 3*E_, E_);
        pkv_pack<<<B_*32, 512, 0, stream>>>(qkv, cv[I_HITS], pscale,
                                            cv[I_PW1] + (size_t)l*6*E_, PTt, Kt, VTf);
        attn11_kernel<<<B_*(N_/2), 512, 0, stream>>>(qkv, PTt, Kt, VTf, cv[I_HITS], maskI, pscale,
                                               cv[I_PB1] + (size_t)l*E_,
                                               cv[I_PW1] + (size_t)l*6*E_,
                                               cv[I_PW2] + (size_t)l*E_*H_,
                                               cv[I_PB2] + (size_t)l*H_,
                                               attnob);
        gemm_bf16<0><<<dim3(4,128), 256, 0, stream>>>(attnob, wto + (size_t)l*E_*E_,
                                                      cv[I_OUT_B] + (size_t)l*E_, tmp, nullptr,
                                                      B_*N_, E_, E_);
        ln_add_kernel<<<B_*N_, 256, 0, stream>>>(feat, tmp, cv[I_N1S] + (size_t)l*E_,
                                                 cv[I_N1B] + (size_t)l*E_, xbuf, xbufb);
        gemm_bf16<1><<<dim3(16,128), 256, 0, stream>>>(xbufb, wt1 + (size_t)l*DFF_*E_,
                                                       cv[I_FB1] + (size_t)l*DFF_, nullptr, ffnhb,
                                                       B_*N_, DFF_, E_);
        gemm_bf16<0><<<dim3(4,128), 256, 0, stream>>>(ffnhb, wt2 + (size_t)l*E_*DFF_,
                                                      cv[I_FB2] + (size_t)l*E_, tmp, nullptr,
                                                      B_*N_, E_, DFF_);
        ln_add_kernel<<<B_*N_, 256, 0, stream>>>(xbuf, tmp, cv[I_N2S] + (size_t)l*E_,
                                                 cv[I_N2B] + (size_t)l*E_, feat, featb);
    }

    pool_kernel<<<B_, 256, 0, stream>>>(feat, maskI, pooled);
    pf_kernel<<<B_, 256, 0, stream>>>(cv[I_PARAMS], cv[I_PFW1], cv[I_PFB1],
                                      cv[I_PFLS], cv[I_PFLB], cv[I_PFW2], cv[I_PFB2], pooled);
    cls_kernel<<<B_, 512, 0, stream>>>(pooled, cv[I_CW1], cv[I_CB1], cv[I_CW2], cv[I_CB2],
                                       cv[I_CW3], cv[I_CB3], (float*)d_out);
}